// Round 1
// baseline (40191.122 us; speedup 1.0000x reference)
//
#include <hip/hip_runtime.h>
#include <hip/hip_bf16.h>
#include <math.h>

// Problem constants
#define BB 8
#define CC 16
#define HH 112
#define WW 112
#define KK 9
#define FS 9
#define WIN 7
#define DIM 160
#define HEADS 5
#define HDIM 32
#define MLPD 640
#define NWIN 256          // (112/7)^2
#define NPOS (BB*HH*WW)   // 100352

// ---------------------------------------------------------------------------
// Kernel A: relu + analysis filter bank -> x3 [B,H,W,160] channels-last
// channel layout: ch = k*16 + c for subbands, 144+c for relu skip
// ---------------------------------------------------------------------------
__global__ __launch_bounds__(256) void ana_kernel(const float* __restrict__ x,
                                                  const float* __restrict__ fana,
                                                  float* __restrict__ x3) {
  __shared__ float tileS[16 * 576];  // 16 ch x 24x24
  __shared__ float fs[729];
  int tid = threadIdx.x;
  int blk = blockIdx.x;
  int b = blk / 49;
  int tile = blk - b * 49;
  int y0 = (tile / 7) * 16, x0 = (tile % 7) * 16;

  for (int i = tid; i < 729; i += 256) fs[i] = fana[i];
  for (int idx = tid; idx < 9216; idx += 256) {
    int c = idx / 576, r = idx - c * 576;
    int ly = r / 24, lx = r - ly * 24;
    int gy = y0 + ly - 4, gx = x0 + lx - 4;
    float v = 0.f;
    if (gy >= 0 && gy < HH && gx >= 0 && gx < WW)
      v = fmaxf(x[(((long)b * CC + c) * HH + gy) * WW + gx], 0.f);
    tileS[idx] = v;
  }
  __syncthreads();

  int ty = tid >> 4, tx = tid & 15;
  long obase = (((long)b * HH + (y0 + ty)) * WW + (x0 + tx)) * DIM;
  for (int c = 0; c < 16; c++) {
    float acc[9];
#pragma unroll
    for (int k = 0; k < 9; k++) acc[k] = 0.f;
    const float* ts = &tileS[c * 576];
    for (int ky = 0; ky < 9; ky++)
      for (int kx = 0; kx < 9; kx++) {
        float v = ts[(ty + ky) * 24 + (tx + kx)];
#pragma unroll
        for (int k = 0; k < 9; k++) acc[k] += v * fs[k * 81 + ky * 9 + kx];
      }
#pragma unroll
    for (int k = 0; k < 9; k++) x3[obase + k * 16 + c] = acc[k];
    x3[obase + 144 + c] = ts[(ty + 4) * 24 + (tx + 4)];  // relu skip
  }
}

// ---------------------------------------------------------------------------
// Kernel B: Swin attention (one block per window), in-place residual on x3
// ---------------------------------------------------------------------------
__global__ __launch_bounds__(256) void attn_kernel(float* __restrict__ x3,
                                                   const float* __restrict__ ln1g,
                                                   const float* __restrict__ ln1b,
                                                   const float* __restrict__ qkvw,
                                                   const float* __restrict__ qkvb,
                                                   const float* __restrict__ projw,
                                                   const float* __restrict__ projb,
                                                   const float* __restrict__ rpb,
                                                   int shift) {
  __shared__ float xn[50 * 161];  // normalized tokens (row 49 = zero pad)
  __shared__ float qb[49 * 33], kb[49 * 33], vb[49 * 33];
  __shared__ float pb[49 * 49];
  __shared__ int spos[49];

  int tid = threadIdx.x;
  int blk = blockIdx.x;
  int b = blk >> 8;          // / 256 windows per image
  int wid = blk & 255;
  int wi = wid >> 4, wj = wid & 15;

  if (tid < 49) {
    int iy = tid / 7, ix = tid - (tid / 7) * 7;
    int hy = (wi * 7 + iy + shift) % HH;
    int wx = (wj * 7 + ix + shift) % WW;
    spos[tid] = (b * HH + hy) * WW + wx;
  }
  __syncthreads();

  for (int idx = tid; idx < 50 * 160; idx += 256) {
    int t = idx / 160, ch = idx - t * 160;
    xn[t * 161 + ch] = (t < 49) ? x3[(long)spos[t] * DIM + ch] : 0.f;
  }
  __syncthreads();

  // LayerNorm1, one thread per token
  if (tid < 49) {
    float s = 0.f, s2 = 0.f;
    for (int i = 0; i < 160; i++) {
      float v = xn[tid * 161 + i];
      s += v; s2 += v * v;
    }
    float mu = s * (1.f / 160.f);
    float var = s2 * (1.f / 160.f) - mu * mu;
    float r = rsqrtf(var + 1e-5f);
    for (int i = 0; i < 160; i++)
      xn[tid * 161 + i] = (xn[tid * 161 + i] - mu) * r * ln1g[i] + ln1b[i];
  }
  __syncthreads();

  // proj accumulators: 7840 outputs over 256 threads
  float pacc[31];
#pragma unroll
  for (int kk = 0; kk < 31; kk++) {
    int o = tid + kk * 256;
    pacc[kk] = (o < 7840) ? projb[o % 160] : 0.f;
  }

  for (int h = 0; h < HEADS; h++) {
    // ---- q,k,v for this head: 96 cols x 2 token-halves on 192 threads ----
    if (tid < 192) {
      int half = tid / 96;
      int col = tid - half * 96;
      int mat = col >> 5;   // 0=q 1=k 2=v
      int d = col & 31;
      int j = mat * 160 + h * 32 + d;
      float* dst = (mat == 0) ? qb : (mat == 1) ? kb : vb;
      int t0 = half * 25;
      int nt = half ? 24 : 25;
      float acc[25];
      float bj = qkvb[j];
#pragma unroll
      for (int t = 0; t < 25; t++) acc[t] = bj;
      for (int i = 0; i < 160; i++) {
        float wv = qkvw[i * 480 + j];
#pragma unroll
        for (int t = 0; t < 25; t++) acc[t] += xn[(t0 + t) * 161 + i] * wv;
      }
      for (int t = 0; t < nt; t++) dst[(t0 + t) * 33 + d] = acc[t];
    }
    __syncthreads();

    // ---- scores + bias + mask ----
    for (int o = tid; o < 2401; o += 256) {
      int i = o / 49, j = o - i * 49;
      float s = 0.f;
#pragma unroll
      for (int d = 0; d < 32; d++) s += qb[i * 33 + d] * kb[j * 33 + d];
      s *= 0.17677669529663687f;  // 32^-0.5
      int iy = i / 7, ix = i - iy * 7, jy = j / 7, jx = j - jy * 7;
      int rel = (iy - jy + 6) * 13 + (ix - jx + 6);
      s += rpb[rel * 5 + h];
      if (shift) {
        int hri = wi * 7 + iy, hrj = wi * 7 + jy;
        int wri = wj * 7 + ix, wrj = wj * 7 + jx;
        int ai = hri < 105 ? 0 : (hri < 109 ? 1 : 2);
        int aj = hrj < 105 ? 0 : (hrj < 109 ? 1 : 2);
        int bi = wri < 105 ? 0 : (wri < 109 ? 1 : 2);
        int bj2 = wrj < 105 ? 0 : (wrj < 109 ? 1 : 2);
        if (ai != aj || bi != bj2) s -= 100.f;
      }
      pb[o] = s;
    }
    __syncthreads();

    // ---- softmax per row ----
    if (tid < 49) {
      float m = -1e30f;
      for (int j = 0; j < 49; j++) m = fmaxf(m, pb[tid * 49 + j]);
      float sum = 0.f;
      for (int j = 0; j < 49; j++) {
        float e = __expf(pb[tid * 49 + j] - m);
        pb[tid * 49 + j] = e;
        sum += e;
      }
      float inv = 1.f / sum;
      for (int j = 0; j < 49; j++) pb[tid * 49 + j] *= inv;
    }
    __syncthreads();

    // ---- out = P @ V, stored into qb (q dead) ----
    for (int o = tid; o < 49 * 32; o += 256) {
      int i = o >> 5, d = o & 31;
      float acc = 0.f;
      for (int j = 0; j < 49; j++) acc += pb[i * 49 + j] * vb[j * 33 + d];
      qb[i * 33 + d] = acc;
    }
    __syncthreads();

    // ---- proj accumulation for this head's 32 dims ----
    const float* pw = projw + (h * 32) * 160;
#pragma unroll
    for (int kk = 0; kk < 31; kk++) {
      int o = tid + kk * 256;
      if (o < 7840) {
        int t = o / 160, c = o - t * 160;
        float a = pacc[kk];
#pragma unroll
        for (int d = 0; d < 32; d++) a += qb[t * 33 + d] * pw[d * 160 + c];
        pacc[kk] = a;
      }
    }
    __syncthreads();  // before next head overwrites qb/kb/vb
  }

  // residual add into x3
#pragma unroll
  for (int kk = 0; kk < 31; kk++) {
    int o = tid + kk * 256;
    if (o < 7840) {
      int t = o / 160, c = o - t * 160;
      long a = (long)spos[t] * DIM + c;
      x3[a] = x3[a] + pacc[kk];
    }
  }
}

// ---------------------------------------------------------------------------
// Kernel C: LN2 + MLP (160->640 gelu ->160) + residual, 16 tokens per block
// ---------------------------------------------------------------------------
__global__ __launch_bounds__(256) void mlp_kernel(float* __restrict__ x3,
                                                  const float* __restrict__ g,
                                                  const float* __restrict__ bb,
                                                  const float* __restrict__ w1,
                                                  const float* __restrict__ b1,
                                                  const float* __restrict__ w2,
                                                  const float* __restrict__ b2) {
  __shared__ float xs[16 * 160];
  __shared__ float lnv[16 * 161];
  __shared__ float h1[16 * 641];
  __shared__ float red[256];
  __shared__ float mu_s[16], rs_s[16];

  int tid = threadIdx.x;
  long p0 = (long)blockIdx.x * 16;
  for (int idx = tid; idx < 2560; idx += 256) xs[idx] = x3[p0 * DIM + idx];
  __syncthreads();

  int t = tid >> 4, l = tid & 15;
  float s1 = 0.f, s2 = 0.f;
  for (int j = 0; j < 10; j++) {
    float v = xs[t * 160 + l + j * 16];
    s1 += v; s2 += v * v;
  }
  red[tid] = s1;
  __syncthreads();
  if (l == 0) {
    float s = 0.f;
    for (int q = 0; q < 16; q++) s += red[t * 16 + q];
    mu_s[t] = s * (1.f / 160.f);
  }
  __syncthreads();
  red[tid] = s2;
  __syncthreads();
  if (l == 0) {
    float s = 0.f;
    for (int q = 0; q < 16; q++) s += red[t * 16 + q];
    float mu = mu_s[t];
    rs_s[t] = rsqrtf(s * (1.f / 160.f) - mu * mu + 1e-5f);
  }
  __syncthreads();

  for (int idx = tid; idx < 2560; idx += 256) {
    int tt = idx / 160, ch = idx - tt * 160;
    lnv[tt * 161 + ch] = (xs[idx] - mu_s[tt]) * rs_s[tt] * g[ch] + bb[ch];
  }
  __syncthreads();

  // h1 = gelu(ln @ w1 + b1): each thread owns up to 3 of 640 cols, all 16 tokens
  for (int rep = 0; rep < 3; rep++) {
    int j = tid + rep * 256;
    if (j < 640) {
      float acc[16];
      float bj = b1[j];
#pragma unroll
      for (int t2 = 0; t2 < 16; t2++) acc[t2] = bj;
      for (int i = 0; i < 160; i++) {
        float wv = w1[i * 640 + j];
#pragma unroll
        for (int t2 = 0; t2 < 16; t2++) acc[t2] += lnv[t2 * 161 + i] * wv;
      }
#pragma unroll
      for (int t2 = 0; t2 < 16; t2++) {
        float a = acc[t2];
        float gel = 0.5f * a * (1.f + tanhf(0.7978845608028654f * (a + 0.044715f * a * a * a)));
        h1[t2 * 641 + j] = gel;
      }
    }
  }
  __syncthreads();

  // out = xs + h1 @ w2 + b2
  if (tid < 160) {
    int c = tid;
    float acc[16];
#pragma unroll
    for (int t2 = 0; t2 < 16; t2++) acc[t2] = xs[t2 * 160 + c] + b2[c];
    for (int j = 0; j < 640; j++) {
      float wv = w2[j * 160 + c];
#pragma unroll
      for (int t2 = 0; t2 < 16; t2++) acc[t2] += h1[t2 * 641 + j] * wv;
    }
#pragma unroll
    for (int t2 = 0; t2 < 16; t2++) x3[(p0 + t2) * DIM + c] = acc[t2];
  }
}

// ---------------------------------------------------------------------------
// Kernel D: y = x3 @ linw + linb  ([pos,160] -> [pos,144] channels-last)
// ---------------------------------------------------------------------------
__global__ __launch_bounds__(256) void lin_kernel(const float* __restrict__ x3,
                                                  const float* __restrict__ linw,
                                                  const float* __restrict__ linb,
                                                  float* __restrict__ y) {
  __shared__ float xs[16 * 160];
  int tid = threadIdx.x;
  long p0 = (long)blockIdx.x * 16;
  for (int idx = tid; idx < 2560; idx += 256) xs[idx] = x3[p0 * DIM + idx];
  __syncthreads();
  if (tid < 144) {
    int j = tid;
    float acc[16];
    float bj = linb[j];
#pragma unroll
    for (int t2 = 0; t2 < 16; t2++) acc[t2] = bj;
    for (int i = 0; i < 160; i++) {
      float wv = linw[i * 144 + j];
#pragma unroll
      for (int t2 = 0; t2 < 16; t2++) acc[t2] += xs[t2 * 160 + i] * wv;
    }
#pragma unroll
    for (int t2 = 0; t2 < 16; t2++) y[(p0 + t2) * 144 + j] = acc[t2];
  }
}

// ---------------------------------------------------------------------------
// Kernel E: synthesis conv, grouped: y_trans[b,h,w,c] = sum_k fsyn[k] * y[..,k*16+c]
// one block per (b, c, 16x16 tile)
// ---------------------------------------------------------------------------
__global__ __launch_bounds__(256) void syn_kernel(const float* __restrict__ y,
                                                  const float* __restrict__ fsyn,
                                                  float* __restrict__ yt) {
  __shared__ float tileS[9 * 576];  // 9 k x 24x24
  __shared__ float fsl[729];
  int tid = threadIdx.x;
  int blk = blockIdx.x;
  int b = blk / 784;
  int rem = blk - b * 784;
  int c = rem / 49;
  int tile = rem - c * 49;
  int y0 = (tile / 7) * 16, x0 = (tile % 7) * 16;

  for (int i = tid; i < 729; i += 256) fsl[i] = fsyn[i];
  for (int idx = tid; idx < 5184; idx += 256) {
    int k = idx / 576, r = idx - k * 576;
    int ly = r / 24, lx = r - ly * 24;
    int gy = y0 + ly - 4, gx = x0 + lx - 4;
    float v = 0.f;
    if (gy >= 0 && gy < HH && gx >= 0 && gx < WW)
      v = y[(((long)b * HH + gy) * WW + gx) * 144 + k * 16 + c];
    tileS[idx] = v;
  }
  __syncthreads();

  int ty = tid >> 4, tx = tid & 15;
  float acc = 0.f;
  for (int k = 0; k < 9; k++) {
    const float* ts = &tileS[k * 576];
    const float* fk = &fsl[k * 81];
    for (int ky = 0; ky < 9; ky++)
#pragma unroll
      for (int kx = 0; kx < 9; kx++)
        acc += ts[(ty + ky) * 24 + (tx + kx)] * fk[ky * 9 + kx];
  }
  yt[(((long)b * HH + (y0 + ty)) * WW + (x0 + tx)) * 16 + c] = acc;
}

// ---------------------------------------------------------------------------
// Kernel F: final 1x1 conv: out[b,co,h,w] = convb[co] + yt.convw[:,0:16] + y.convw[:,16:160]
// ---------------------------------------------------------------------------
__global__ __launch_bounds__(256) void final_kernel(const float* __restrict__ yt,
                                                    const float* __restrict__ y,
                                                    const float* __restrict__ convw,
                                                    const float* __restrict__ convb,
                                                    float* __restrict__ out) {
  long pos = (long)blockIdx.x * 256 + threadIdx.x;
  if (pos >= NPOS) return;
  int b = (int)(pos / (HH * WW));
  int hw = (int)(pos - (long)b * HH * WW);

  float acc[16];
#pragma unroll
  for (int co = 0; co < 16; co++) acc[co] = convb[co];
  for (int c = 0; c < 16; c++) {
    float v = yt[pos * 16 + c];
#pragma unroll
    for (int co = 0; co < 16; co++) acc[co] += v * convw[co * 160 + c];
  }
  for (int j = 0; j < 144; j++) {
    float v = y[pos * 144 + j];
#pragma unroll
    for (int co = 0; co < 16; co++) acc[co] += v * convw[co * 160 + 16 + j];
  }
#pragma unroll
  for (int co = 0; co < 16; co++)
    out[(((long)b * 16 + co) * HH * WW) + hw] = acc[co];
}

// ---------------------------------------------------------------------------
extern "C" void kernel_launch(void* const* d_in, const int* in_sizes, int n_in,
                              void* d_out, int out_size, void* d_ws, size_t ws_size,
                              hipStream_t stream) {
  const float* x     = (const float*)d_in[0];
  const float* fana  = (const float*)d_in[1];
  const float* fsyn  = (const float*)d_in[2];
  const float* ln1g  = (const float*)d_in[3];
  const float* ln1b  = (const float*)d_in[4];
  const float* qkvw  = (const float*)d_in[5];
  const float* qkvb  = (const float*)d_in[6];
  const float* projw = (const float*)d_in[7];
  const float* projb = (const float*)d_in[8];
  const float* rpb   = (const float*)d_in[9];
  const float* ln2g  = (const float*)d_in[10];
  const float* ln2b  = (const float*)d_in[11];
  const float* w1    = (const float*)d_in[12];
  const float* b1    = (const float*)d_in[13];
  const float* w2    = (const float*)d_in[14];
  const float* b2    = (const float*)d_in[15];
  const float* linw  = (const float*)d_in[16];
  const float* linb  = (const float*)d_in[17];
  const float* convw = (const float*)d_in[18];
  const float* convb = (const float*)d_in[19];
  float* out = (float*)d_out;

  char* ws = (char*)d_ws;
  float* x3 = (float*)ws;                        // NPOS*160*4 = 64,225,280 B
  float* y  = (float*)(ws + 64225280);           // NPOS*144*4 = 57,802,752 B
  float* yt = (float*)ws;                        // aliases x3 (dead after lin)

  ana_kernel<<<BB * 49, 256, 0, stream>>>(x, fana, x3);
  for (int i = 0; i < 2; i++) {
    int shift = i ? (WIN / 2) : 0;
    attn_kernel<<<BB * NWIN, 256, 0, stream>>>(x3, ln1g + i * 160, ln1b + i * 160,
                                               qkvw + i * 160 * 480, qkvb + i * 480,
                                               projw + i * 160 * 160, projb + i * 160,
                                               rpb + i * 169 * 5, shift);
    mlp_kernel<<<NPOS / 16, 256, 0, stream>>>(x3, ln2g + i * 160, ln2b + i * 160,
                                              w1 + i * 160 * 640, b1 + i * 640,
                                              w2 + i * 640 * 160, b2 + i * 160);
  }
  lin_kernel<<<NPOS / 16, 256, 0, stream>>>(x3, linw, linb, y);
  syn_kernel<<<BB * 16 * 49, 256, 0, stream>>>(y, fsyn, yt);
  final_kernel<<<(NPOS + 255) / 256, 256, 0, stream>>>(yt, y, convw, convb, out);
}

// Round 2
// 5002.204 us; speedup vs baseline: 8.0347x; 8.0347x over previous
//
#include <hip/hip_runtime.h>
#include <hip/hip_bf16.h>
#include <math.h>

#define BB 8
#define CC 16
#define HH 112
#define WW 112
#define KK 9
#define FS 9
#define WIN 7
#define DIM 160
#define HEADS 5
#define HDIM 32
#define MLPD 640
#define NWIN 256          // (112/7)^2
#define NPOS (BB*HH*WW)   // 100352
#define NTOK (2048*49)    // == NPOS, window-ordered

// ---------------------------------------------------------------------------
// Kernel A: relu + analysis filter bank -> x3 [B,H,W,160] channels-last
// ---------------------------------------------------------------------------
__global__ __launch_bounds__(256) void ana_kernel(const float* __restrict__ x,
                                                  const float* __restrict__ fana,
                                                  float* __restrict__ x3) {
  __shared__ float tileS[16 * 576];  // 16 ch x 24x24
  __shared__ float fs[729];
  int tid = threadIdx.x;
  int blk = blockIdx.x;
  int b = blk / 49;
  int tile = blk - b * 49;
  int y0 = (tile / 7) * 16, x0 = (tile % 7) * 16;

  for (int i = tid; i < 729; i += 256) fs[i] = fana[i];
  for (int idx = tid; idx < 9216; idx += 256) {
    int c = idx / 576, r = idx - c * 576;
    int ly = r / 24, lx = r - ly * 24;
    int gy = y0 + ly - 4, gx = x0 + lx - 4;
    float v = 0.f;
    if (gy >= 0 && gy < HH && gx >= 0 && gx < WW)
      v = fmaxf(x[(((long)b * CC + c) * HH + gy) * WW + gx], 0.f);
    tileS[idx] = v;
  }
  __syncthreads();

  int ty = tid >> 4, tx = tid & 15;
  long obase = (((long)b * HH + (y0 + ty)) * WW + (x0 + tx)) * DIM;
  for (int c = 0; c < 16; c++) {
    float acc[9];
#pragma unroll
    for (int k = 0; k < 9; k++) acc[k] = 0.f;
    const float* ts = &tileS[c * 576];
    for (int ky = 0; ky < 9; ky++)
      for (int kx = 0; kx < 9; kx++) {
        float v = ts[(ty + ky) * 24 + (tx + kx)];
#pragma unroll
        for (int k = 0; k < 9; k++) acc[k] += v * fs[k * 81 + ky * 9 + kx];
      }
#pragma unroll
    for (int k = 0; k < 9; k++) x3[obase + k * 16 + c] = acc[k];
    x3[obase + 144 + c] = ts[(ty + 4) * 24 + (tx + 4)];  // relu skip
  }
}

// ---------------------------------------------------------------------------
// spos helper: window-ordered flat token p -> source position in [B,H,W]
// ---------------------------------------------------------------------------
__device__ __forceinline__ int token_pos(int p, int shift) {
  int w = p / 49;
  int t = p - w * 49;
  int b = w >> 8;
  int wid = w & 255;
  int wi = wid >> 4, wj = wid & 15;
  int iy = t / 7, ix = t - (t / 7) * 7;
  int hy = (wi * 7 + iy + shift) % HH;
  int wx = (wj * 7 + ix + shift) % WW;
  return (b * HH + hy) * WW + wx;
}

// ---------------------------------------------------------------------------
// Kernel B1: LN1 + qkv GEMM. 16 tokens/block (window-ordered), out [p,480]
// ---------------------------------------------------------------------------
__global__ __launch_bounds__(256) void qkv_kernel(const float* __restrict__ x3,
                                                  const float* __restrict__ g,
                                                  const float* __restrict__ bb,
                                                  const float* __restrict__ qkvw,
                                                  const float* __restrict__ qkvb,
                                                  float* __restrict__ qkvbuf,
                                                  int shift) {
  __shared__ float xs[16 * 160];
  __shared__ float lnv[16 * 161];
  __shared__ float red[256];
  __shared__ float mu_s[16], rs_s[16];
  __shared__ int spos[16];

  int tid = threadIdx.x;
  int p0 = blockIdx.x * 16;
  if (tid < 16) spos[tid] = token_pos(p0 + tid, shift);
  __syncthreads();

  for (int idx = tid; idx < 2560; idx += 256) {
    int t = idx / 160, ch = idx - t * 160;
    xs[idx] = x3[(long)spos[t] * DIM + ch];
  }
  __syncthreads();

  int t = tid >> 4, l = tid & 15;
  float s1 = 0.f, s2 = 0.f;
  for (int j = 0; j < 10; j++) {
    float v = xs[t * 160 + l + j * 16];
    s1 += v; s2 += v * v;
  }
  red[tid] = s1;
  __syncthreads();
  if (l == 0) {
    float s = 0.f;
    for (int q = 0; q < 16; q++) s += red[t * 16 + q];
    mu_s[t] = s * (1.f / 160.f);
  }
  __syncthreads();
  red[tid] = s2;
  __syncthreads();
  if (l == 0) {
    float s = 0.f;
    for (int q = 0; q < 16; q++) s += red[t * 16 + q];
    float mu = mu_s[t];
    rs_s[t] = rsqrtf(s * (1.f / 160.f) - mu * mu + 1e-5f);
  }
  __syncthreads();

  for (int idx = tid; idx < 2560; idx += 256) {
    int tt = idx / 160, ch = idx - tt * 160;
    lnv[tt * 161 + ch] = (xs[idx] - mu_s[tt]) * rs_s[tt] * g[ch] + bb[ch];
  }
  __syncthreads();

  // GEMM [16,160] @ [160,480]; thread owns cols j0=tid, j1=tid+256 (if <480)
  int j0 = tid, j1 = tid + 256;
  bool h1 = (j1 < 480);
  float acc0[16], acc1[16];
  float b0 = qkvb[j0];
  float b1v = h1 ? qkvb[j1] : 0.f;
#pragma unroll
  for (int tt = 0; tt < 16; tt++) { acc0[tt] = b0; acc1[tt] = b1v; }
  for (int i = 0; i < 160; i++) {
    float w0 = qkvw[i * 480 + j0];
    float w1 = h1 ? qkvw[i * 480 + j1] : 0.f;
#pragma unroll
    for (int tt = 0; tt < 16; tt++) {
      float xv = lnv[tt * 161 + i];
      acc0[tt] += xv * w0;
      acc1[tt] += xv * w1;
    }
  }
#pragma unroll
  for (int tt = 0; tt < 16; tt++) {
    qkvbuf[(long)(p0 + tt) * 480 + j0] = acc0[tt];
    if (h1) qkvbuf[(long)(p0 + tt) * 480 + j1] = acc1[tt];
  }
}

// ---------------------------------------------------------------------------
// Kernel B2: per-window attention core. Reads q,k,v head slices; writes
// attention output into the (dead) q-slot columns of qkvbuf.
// ---------------------------------------------------------------------------
__global__ __launch_bounds__(256) void attn_core(float* __restrict__ qkvbuf,
                                                 const float* __restrict__ rpb,
                                                 int shift) {
  __shared__ float qs[49 * 33], ks[49 * 33], vs[49 * 33];
  __shared__ float pb[49 * 49];

  int tid = threadIdx.x;
  int w = blockIdx.x;
  int wid = w & 255;
  int wi = wid >> 4, wj = wid & 15;
  long base = (long)w * 49 * 480;

  for (int h = 0; h < HEADS; h++) {
    // load q,k,v [49,32] for this head
    for (int idx = tid; idx < 4704; idx += 256) {
      int m = idx / 1568;
      int r = idx - m * 1568;
      int t = r >> 5, d = r & 31;
      float v = qkvbuf[base + (long)t * 480 + m * 160 + h * 32 + d];
      float* dst = (m == 0) ? qs : (m == 1) ? ks : vs;
      dst[t * 33 + d] = v;
    }
    __syncthreads();

    // scores + bias + mask
    for (int o = tid; o < 2401; o += 256) {
      int i = o / 49, j = o - i * 49;
      float s = 0.f;
#pragma unroll
      for (int d = 0; d < 32; d++) s += qs[i * 33 + d] * ks[j * 33 + d];
      s *= 0.17677669529663687f;
      int iy = i / 7, ix = i - iy * 7, jy = j / 7, jx = j - jy * 7;
      int rel = (iy - jy + 6) * 13 + (ix - jx + 6);
      s += rpb[rel * 5 + h];
      if (shift) {
        int hri = wi * 7 + iy, hrj = wi * 7 + jy;
        int wri = wj * 7 + ix, wrj = wj * 7 + jx;
        int ai = hri < 105 ? 0 : (hri < 109 ? 1 : 2);
        int aj = hrj < 105 ? 0 : (hrj < 109 ? 1 : 2);
        int bi = wri < 105 ? 0 : (wri < 109 ? 1 : 2);
        int bj2 = wrj < 105 ? 0 : (wrj < 109 ? 1 : 2);
        if (ai != aj || bi != bj2) s -= 100.f;
      }
      pb[o] = s;
    }
    __syncthreads();

    // softmax per row
    if (tid < 49) {
      float m = -1e30f;
      for (int j = 0; j < 49; j++) m = fmaxf(m, pb[tid * 49 + j]);
      float sum = 0.f;
      for (int j = 0; j < 49; j++) {
        float e = __expf(pb[tid * 49 + j] - m);
        pb[tid * 49 + j] = e;
        sum += e;
      }
      float inv = 1.f / sum;
      for (int j = 0; j < 49; j++) pb[tid * 49 + j] *= inv;
    }
    __syncthreads();

    // out = P @ V -> q-slot columns [h*32 .. h*32+31]
    for (int o = tid; o < 1568; o += 256) {
      int i = o >> 5, d = o & 31;
      float acc = 0.f;
      for (int j = 0; j < 49; j++) acc += pb[i * 49 + j] * vs[j * 33 + d];
      qkvbuf[base + (long)i * 480 + h * 32 + d] = acc;
    }
    __syncthreads();  // before next head reloads qs/ks/vs
  }
}

// ---------------------------------------------------------------------------
// Kernel B3: proj + residual scatter-add. 16 tokens/block (window-ordered).
// attn output lives in qkvbuf[p*480 + 0:160].
// ---------------------------------------------------------------------------
__global__ __launch_bounds__(256) void proj_res(const float* __restrict__ qkvbuf,
                                                const float* __restrict__ projw,
                                                const float* __restrict__ projb,
                                                float* __restrict__ x3,
                                                int shift) {
  __shared__ float ao[16 * 160];
  __shared__ int spos[16];
  int tid = threadIdx.x;
  int p0 = blockIdx.x * 16;
  if (tid < 16) spos[tid] = token_pos(p0 + tid, shift);
  for (int idx = tid; idx < 2560; idx += 256) {
    int t = idx / 160, ch = idx - t * 160;
    ao[idx] = qkvbuf[(long)(p0 + t) * 480 + ch];
  }
  __syncthreads();

  if (tid < 160) {
    int c = tid;
    float acc[16];
    float bc = projb[c];
#pragma unroll
    for (int t = 0; t < 16; t++) acc[t] = bc;
    for (int d = 0; d < 160; d++) {
      float wv = projw[d * 160 + c];
#pragma unroll
      for (int t = 0; t < 16; t++) acc[t] += ao[t * 160 + d] * wv;
    }
#pragma unroll
    for (int t = 0; t < 16; t++) {
      long a = (long)spos[t] * DIM + c;
      x3[a] = x3[a] + acc[t];
    }
  }
}

// ---------------------------------------------------------------------------
// Kernel C: LN2 + MLP (160->640 gelu ->160) + residual, 16 tokens/block
// ---------------------------------------------------------------------------
__global__ __launch_bounds__(256) void mlp_kernel(float* __restrict__ x3,
                                                  const float* __restrict__ g,
                                                  const float* __restrict__ bb,
                                                  const float* __restrict__ w1,
                                                  const float* __restrict__ b1,
                                                  const float* __restrict__ w2,
                                                  const float* __restrict__ b2) {
  __shared__ float xs[16 * 160];
  __shared__ float lnv[16 * 161];
  __shared__ float h1[16 * 641];
  __shared__ float red[256];
  __shared__ float mu_s[16], rs_s[16];

  int tid = threadIdx.x;
  long p0 = (long)blockIdx.x * 16;
  for (int idx = tid; idx < 2560; idx += 256) xs[idx] = x3[p0 * DIM + idx];
  __syncthreads();

  int t = tid >> 4, l = tid & 15;
  float s1 = 0.f, s2 = 0.f;
  for (int j = 0; j < 10; j++) {
    float v = xs[t * 160 + l + j * 16];
    s1 += v; s2 += v * v;
  }
  red[tid] = s1;
  __syncthreads();
  if (l == 0) {
    float s = 0.f;
    for (int q = 0; q < 16; q++) s += red[t * 16 + q];
    mu_s[t] = s * (1.f / 160.f);
  }
  __syncthreads();
  red[tid] = s2;
  __syncthreads();
  if (l == 0) {
    float s = 0.f;
    for (int q = 0; q < 16; q++) s += red[t * 16 + q];
    float mu = mu_s[t];
    rs_s[t] = rsqrtf(s * (1.f / 160.f) - mu * mu + 1e-5f);
  }
  __syncthreads();

  for (int idx = tid; idx < 2560; idx += 256) {
    int tt = idx / 160, ch = idx - tt * 160;
    lnv[tt * 161 + ch] = (xs[idx] - mu_s[tt]) * rs_s[tt] * g[ch] + bb[ch];
  }
  __syncthreads();

  // fc1 + gelu: thread owns 3 cols (j, j+256, j+512<640 iff tid<128)
  {
    int j0 = tid, j1 = tid + 256, j2 = tid + 512;
    bool has2 = (j2 < 640);
    float a0[16], a1[16], a2[16];
    float c0 = b1[j0], c1 = b1[j1], c2 = has2 ? b1[j2] : 0.f;
#pragma unroll
    for (int tt = 0; tt < 16; tt++) { a0[tt] = c0; a1[tt] = c1; a2[tt] = c2; }
    for (int i = 0; i < 160; i++) {
      float w0 = w1[i * 640 + j0];
      float wv1 = w1[i * 640 + j1];
      float wv2 = has2 ? w1[i * 640 + j2] : 0.f;
#pragma unroll
      for (int tt = 0; tt < 16; tt++) {
        float xv = lnv[tt * 161 + i];
        a0[tt] += xv * w0;
        a1[tt] += xv * wv1;
        a2[tt] += xv * wv2;
      }
    }
#pragma unroll
    for (int tt = 0; tt < 16; tt++) {
      float a = a0[tt];
      h1[tt * 641 + j0] = 0.5f * a * (1.f + tanhf(0.7978845608028654f * (a + 0.044715f * a * a * a)));
      a = a1[tt];
      h1[tt * 641 + j1] = 0.5f * a * (1.f + tanhf(0.7978845608028654f * (a + 0.044715f * a * a * a)));
      if (has2) {
        a = a2[tt];
        h1[tt * 641 + j2] = 0.5f * a * (1.f + tanhf(0.7978845608028654f * (a + 0.044715f * a * a * a)));
      }
    }
  }
  __syncthreads();

  // fc2 + residual
  if (tid < 160) {
    int c = tid;
    float acc[16];
#pragma unroll
    for (int t2 = 0; t2 < 16; t2++) acc[t2] = xs[t2 * 160 + c] + b2[c];
    for (int j = 0; j < 640; j++) {
      float wv = w2[j * 160 + c];
#pragma unroll
      for (int t2 = 0; t2 < 16; t2++) acc[t2] += h1[t2 * 641 + j] * wv;
    }
#pragma unroll
    for (int t2 = 0; t2 < 16; t2++) x3[(p0 + t2) * DIM + c] = acc[t2];
  }
}

// ---------------------------------------------------------------------------
// Kernel D: y = x3 @ linw + linb  ([pos,160] -> [pos,144])
// ---------------------------------------------------------------------------
__global__ __launch_bounds__(256) void lin_kernel(const float* __restrict__ x3,
                                                  const float* __restrict__ linw,
                                                  const float* __restrict__ linb,
                                                  float* __restrict__ y) {
  __shared__ float xs[16 * 160];
  int tid = threadIdx.x;
  long p0 = (long)blockIdx.x * 16;
  for (int idx = tid; idx < 2560; idx += 256) xs[idx] = x3[p0 * DIM + idx];
  __syncthreads();
  if (tid < 144) {
    int j = tid;
    float acc[16];
    float bj = linb[j];
#pragma unroll
    for (int t2 = 0; t2 < 16; t2++) acc[t2] = bj;
    for (int i = 0; i < 160; i++) {
      float wv = linw[i * 144 + j];
#pragma unroll
      for (int t2 = 0; t2 < 16; t2++) acc[t2] += xs[t2 * 160 + i] * wv;
    }
#pragma unroll
    for (int t2 = 0; t2 < 16; t2++) y[(p0 + t2) * 144 + j] = acc[t2];
  }
}

// ---------------------------------------------------------------------------
// Kernel E: synthesis conv (grouped 9-band)
// ---------------------------------------------------------------------------
__global__ __launch_bounds__(256) void syn_kernel(const float* __restrict__ y,
                                                  const float* __restrict__ fsyn,
                                                  float* __restrict__ yt) {
  __shared__ float tileS[9 * 576];
  __shared__ float fsl[729];
  int tid = threadIdx.x;
  int blk = blockIdx.x;
  int b = blk / 784;
  int rem = blk - b * 784;
  int c = rem / 49;
  int tile = rem - c * 49;
  int y0 = (tile / 7) * 16, x0 = (tile % 7) * 16;

  for (int i = tid; i < 729; i += 256) fsl[i] = fsyn[i];
  for (int idx = tid; idx < 5184; idx += 256) {
    int k = idx / 576, r = idx - k * 576;
    int ly = r / 24, lx = r - ly * 24;
    int gy = y0 + ly - 4, gx = x0 + lx - 4;
    float v = 0.f;
    if (gy >= 0 && gy < HH && gx >= 0 && gx < WW)
      v = y[(((long)b * HH + gy) * WW + gx) * 144 + k * 16 + c];
    tileS[idx] = v;
  }
  __syncthreads();

  int ty = tid >> 4, tx = tid & 15;
  float acc = 0.f;
  for (int k = 0; k < 9; k++) {
    const float* ts = &tileS[k * 576];
    const float* fk = &fsl[k * 81];
    for (int ky = 0; ky < 9; ky++)
#pragma unroll
      for (int kx = 0; kx < 9; kx++)
        acc += ts[(ty + ky) * 24 + (tx + kx)] * fk[ky * 9 + kx];
  }
  yt[(((long)b * HH + (y0 + ty)) * WW + (x0 + tx)) * 16 + c] = acc;
}

// ---------------------------------------------------------------------------
// Kernel F: final 1x1 conv -> out [B,16,H,W]
// ---------------------------------------------------------------------------
__global__ __launch_bounds__(256) void final_kernel(const float* __restrict__ yt,
                                                    const float* __restrict__ y,
                                                    const float* __restrict__ convw,
                                                    const float* __restrict__ convb,
                                                    float* __restrict__ out) {
  long pos = (long)blockIdx.x * 256 + threadIdx.x;
  if (pos >= NPOS) return;
  int b = (int)(pos / (HH * WW));
  int hw = (int)(pos - (long)b * HH * WW);

  float acc[16];
#pragma unroll
  for (int co = 0; co < 16; co++) acc[co] = convb[co];
  for (int c = 0; c < 16; c++) {
    float v = yt[pos * 16 + c];
#pragma unroll
    for (int co = 0; co < 16; co++) acc[co] += v * convw[co * 160 + c];
  }
  for (int j = 0; j < 144; j++) {
    float v = y[pos * 144 + j];
#pragma unroll
    for (int co = 0; co < 16; co++) acc[co] += v * convw[co * 160 + 16 + j];
  }
#pragma unroll
  for (int co = 0; co < 16; co++)
    out[(((long)b * 16 + co) * HH * WW) + hw] = acc[co];
}

// ---------------------------------------------------------------------------
extern "C" void kernel_launch(void* const* d_in, const int* in_sizes, int n_in,
                              void* d_out, int out_size, void* d_ws, size_t ws_size,
                              hipStream_t stream) {
  const float* x     = (const float*)d_in[0];
  const float* fana  = (const float*)d_in[1];
  const float* fsyn  = (const float*)d_in[2];
  const float* ln1g  = (const float*)d_in[3];
  const float* ln1b  = (const float*)d_in[4];
  const float* qkvw  = (const float*)d_in[5];
  const float* qkvb  = (const float*)d_in[6];
  const float* projw = (const float*)d_in[7];
  const float* projb = (const float*)d_in[8];
  const float* rpb   = (const float*)d_in[9];
  const float* ln2g  = (const float*)d_in[10];
  const float* ln2b  = (const float*)d_in[11];
  const float* w1    = (const float*)d_in[12];
  const float* b1    = (const float*)d_in[13];
  const float* w2    = (const float*)d_in[14];
  const float* b2    = (const float*)d_in[15];
  const float* linw  = (const float*)d_in[16];
  const float* linb  = (const float*)d_in[17];
  const float* convw = (const float*)d_in[18];
  const float* convb = (const float*)d_in[19];
  float* out = (float*)d_out;

  char* ws = (char*)d_ws;
  float* x3     = (float*)ws;                    // 64,225,280 B
  float* qkvbuf = (float*)(ws + 64225280);       // 192,675,840 B (NTOK*480*4)
  float* y      = (float*)(ws + 64225280);       // aliases qkvbuf (dead by lin)
  float* yt     = (float*)ws;                    // aliases x3 (dead after lin)

  ana_kernel<<<BB * 49, 256, 0, stream>>>(x, fana, x3);
  for (int i = 0; i < 2; i++) {
    int shift = i ? (WIN / 2) : 0;
    qkv_kernel<<<NPOS / 16, 256, 0, stream>>>(x3, ln1g + i * 160, ln1b + i * 160,
                                              qkvw + i * 160 * 480, qkvb + i * 480,
                                              qkvbuf, shift);
    attn_core<<<BB * NWIN, 256, 0, stream>>>(qkvbuf, rpb + i * 169 * 5, shift);
    proj_res<<<NPOS / 16, 256, 0, stream>>>(qkvbuf, projw + i * 160 * 160,
                                            projb + i * 160, x3, shift);
    mlp_kernel<<<NPOS / 16, 256, 0, stream>>>(x3, ln2g + i * 160, ln2b + i * 160,
                                              w1 + i * 160 * 640, b1 + i * 640,
                                              w2 + i * 640 * 160, b2 + i * 160);
  }
  lin_kernel<<<NPOS / 16, 256, 0, stream>>>(x3, linw, linb, y);
  syn_kernel<<<BB * 16 * 49, 256, 0, stream>>>(y, fsyn, yt);
  final_kernel<<<(NPOS + 255) / 256, 256, 0, stream>>>(yt, y, convw, convb, out);
}

// Round 3
// 3021.550 us; speedup vs baseline: 13.3015x; 1.6555x over previous
//
#include <hip/hip_runtime.h>
#include <hip/hip_bf16.h>
#include <math.h>

#define BB 8
#define CC 16
#define HH 112
#define WW 112
#define KK 9
#define FS 9
#define WIN 7
#define DIM 160
#define HEADS 5
#define HDIM 32
#define MLPD 640
#define NWIN 256          // (112/7)^2
#define NPOS (BB*HH*WW)   // 100352

typedef __attribute__((ext_vector_type(8))) short short8;
typedef __attribute__((ext_vector_type(4))) float floatx4;

__device__ __forceinline__ unsigned short f2bf(float f) {
  union { float f; unsigned u; } v; v.f = f;
  unsigned r = v.u + 0x7fffu + ((v.u >> 16) & 1u);
  return (unsigned short)(r >> 16);
}

// ---------------------------------------------------------------------------
// Kernel A: relu + analysis filter bank -> x3 [B,H,W,160] channels-last
// ---------------------------------------------------------------------------
__global__ __launch_bounds__(256) void ana_kernel(const float* __restrict__ x,
                                                  const float* __restrict__ fana,
                                                  float* __restrict__ x3) {
  __shared__ float tileS[16 * 576];  // 16 ch x 24x24
  __shared__ float fs[729];
  int tid = threadIdx.x;
  int blk = blockIdx.x;
  int b = blk / 49;
  int tile = blk - b * 49;
  int y0 = (tile / 7) * 16, x0 = (tile % 7) * 16;

  for (int i = tid; i < 729; i += 256) fs[i] = fana[i];
  for (int idx = tid; idx < 9216; idx += 256) {
    int c = idx / 576, r = idx - c * 576;
    int ly = r / 24, lx = r - ly * 24;
    int gy = y0 + ly - 4, gx = x0 + lx - 4;
    float v = 0.f;
    if (gy >= 0 && gy < HH && gx >= 0 && gx < WW)
      v = fmaxf(x[(((long)b * CC + c) * HH + gy) * WW + gx], 0.f);
    tileS[idx] = v;
  }
  __syncthreads();

  int ty = tid >> 4, tx = tid & 15;
  long obase = (((long)b * HH + (y0 + ty)) * WW + (x0 + tx)) * DIM;
  for (int c = 0; c < 16; c++) {
    float acc[9];
#pragma unroll
    for (int k = 0; k < 9; k++) acc[k] = 0.f;
    const float* ts = &tileS[c * 576];
    for (int ky = 0; ky < 9; ky++)
      for (int kx = 0; kx < 9; kx++) {
        float v = ts[(ty + ky) * 24 + (tx + kx)];
#pragma unroll
        for (int k = 0; k < 9; k++) acc[k] += v * fs[k * 81 + ky * 9 + kx];
      }
#pragma unroll
    for (int k = 0; k < 9; k++) x3[obase + k * 16 + c] = acc[k];
    x3[obase + 144 + c] = ts[(ty + 4) * 24 + (tx + 4)];  // relu skip
  }
}

// ---------------------------------------------------------------------------
// token_pos: window-ordered flat token p -> source position in [B,H,W]
// ---------------------------------------------------------------------------
__device__ __forceinline__ int token_pos(int p, int shift) {
  int w = p / 49;
  int t = p - w * 49;
  int b = w >> 8;
  int wid = w & 255;
  int wi = wid >> 4, wj = wid & 15;
  int iy = t / 7, ix = t - (t / 7) * 7;
  int hy = (wi * 7 + iy + shift) % HH;
  int wx = (wj * 7 + ix + shift) % WW;
  return (b * HH + hy) * WW + wx;
}

// ---------------------------------------------------------------------------
// Kernel B1: LN1 + qkv GEMM (fp32). 16 tokens/block, out [p,480]
// ---------------------------------------------------------------------------
__global__ __launch_bounds__(256) void qkv_kernel(const float* __restrict__ x3,
                                                  const float* __restrict__ g,
                                                  const float* __restrict__ bb,
                                                  const float* __restrict__ qkvw,
                                                  const float* __restrict__ qkvb,
                                                  float* __restrict__ qkvbuf,
                                                  int shift) {
  __shared__ float xs[16 * 160];
  __shared__ float lnv[16 * 161];
  __shared__ float red[256];
  __shared__ float mu_s[16], rs_s[16];
  __shared__ int spos[16];

  int tid = threadIdx.x;
  int p0 = blockIdx.x * 16;
  if (tid < 16) spos[tid] = token_pos(p0 + tid, shift);
  __syncthreads();

  for (int idx = tid; idx < 2560; idx += 256) {
    int t = idx / 160, ch = idx - t * 160;
    xs[idx] = x3[(long)spos[t] * DIM + ch];
  }
  __syncthreads();

  int t = tid >> 4, l = tid & 15;
  float s1 = 0.f, s2 = 0.f;
  for (int j = 0; j < 10; j++) {
    float v = xs[t * 160 + l + j * 16];
    s1 += v; s2 += v * v;
  }
  red[tid] = s1;
  __syncthreads();
  if (l == 0) {
    float s = 0.f;
    for (int q = 0; q < 16; q++) s += red[t * 16 + q];
    mu_s[t] = s * (1.f / 160.f);
  }
  __syncthreads();
  red[tid] = s2;
  __syncthreads();
  if (l == 0) {
    float s = 0.f;
    for (int q = 0; q < 16; q++) s += red[t * 16 + q];
    float mu = mu_s[t];
    rs_s[t] = rsqrtf(s * (1.f / 160.f) - mu * mu + 1e-5f);
  }
  __syncthreads();

  for (int idx = tid; idx < 2560; idx += 256) {
    int tt = idx / 160, ch = idx - tt * 160;
    lnv[tt * 161 + ch] = (xs[idx] - mu_s[tt]) * rs_s[tt] * g[ch] + bb[ch];
  }
  __syncthreads();

  int j0 = tid, j1 = tid + 256;
  bool h1 = (j1 < 480);
  float acc0[16], acc1[16];
  float b0 = qkvb[j0];
  float b1v = h1 ? qkvb[j1] : 0.f;
#pragma unroll
  for (int tt = 0; tt < 16; tt++) { acc0[tt] = b0; acc1[tt] = b1v; }
  for (int i = 0; i < 160; i++) {
    float w0 = qkvw[i * 480 + j0];
    float w1 = h1 ? qkvw[i * 480 + j1] : 0.f;
#pragma unroll
    for (int tt = 0; tt < 16; tt++) {
      float xv = lnv[tt * 161 + i];
      acc0[tt] += xv * w0;
      acc1[tt] += xv * w1;
    }
  }
#pragma unroll
  for (int tt = 0; tt < 16; tt++) {
    qkvbuf[(long)(p0 + tt) * 480 + j0] = acc0[tt];
    if (h1) qkvbuf[(long)(p0 + tt) * 480 + j1] = acc1[tt];
  }
}

// ---------------------------------------------------------------------------
// Kernel B2: per-window attention core (fp32)
// ---------------------------------------------------------------------------
__global__ __launch_bounds__(256) void attn_core(float* __restrict__ qkvbuf,
                                                 const float* __restrict__ rpb,
                                                 int shift) {
  __shared__ float qs[49 * 33], ks[49 * 33], vs[49 * 33];
  __shared__ float pb[49 * 49];

  int tid = threadIdx.x;
  int w = blockIdx.x;
  int wid = w & 255;
  int wi = wid >> 4, wj = wid & 15;
  long base = (long)w * 49 * 480;

  for (int h = 0; h < HEADS; h++) {
    for (int idx = tid; idx < 4704; idx += 256) {
      int m = idx / 1568;
      int r = idx - m * 1568;
      int t = r >> 5, d = r & 31;
      float v = qkvbuf[base + (long)t * 480 + m * 160 + h * 32 + d];
      float* dst = (m == 0) ? qs : (m == 1) ? ks : vs;
      dst[t * 33 + d] = v;
    }
    __syncthreads();

    for (int o = tid; o < 2401; o += 256) {
      int i = o / 49, j = o - i * 49;
      float s = 0.f;
#pragma unroll
      for (int d = 0; d < 32; d++) s += qs[i * 33 + d] * ks[j * 33 + d];
      s *= 0.17677669529663687f;
      int iy = i / 7, ix = i - iy * 7, jy = j / 7, jx = j - jy * 7;
      int rel = (iy - jy + 6) * 13 + (ix - jx + 6);
      s += rpb[rel * 5 + h];
      if (shift) {
        int hri = wi * 7 + iy, hrj = wi * 7 + jy;
        int wri = wj * 7 + ix, wrj = wj * 7 + jx;
        int ai = hri < 105 ? 0 : (hri < 109 ? 1 : 2);
        int aj = hrj < 105 ? 0 : (hrj < 109 ? 1 : 2);
        int bi = wri < 105 ? 0 : (wri < 109 ? 1 : 2);
        int bj2 = wrj < 105 ? 0 : (wrj < 109 ? 1 : 2);
        if (ai != aj || bi != bj2) s -= 100.f;
      }
      pb[o] = s;
    }
    __syncthreads();

    if (tid < 49) {
      float m = -1e30f;
      for (int j = 0; j < 49; j++) m = fmaxf(m, pb[tid * 49 + j]);
      float sum = 0.f;
      for (int j = 0; j < 49; j++) {
        float e = __expf(pb[tid * 49 + j] - m);
        pb[tid * 49 + j] = e;
        sum += e;
      }
      float inv = 1.f / sum;
      for (int j = 0; j < 49; j++) pb[tid * 49 + j] *= inv;
    }
    __syncthreads();

    for (int o = tid; o < 1568; o += 256) {
      int i = o >> 5, d = o & 31;
      float acc = 0.f;
      for (int j = 0; j < 49; j++) acc += pb[i * 49 + j] * vs[j * 33 + d];
      qkvbuf[base + (long)i * 480 + h * 32 + d] = acc;
    }
    __syncthreads();
  }
}

// ---------------------------------------------------------------------------
// Kernel B3: proj + residual scatter-add (fp32)
// ---------------------------------------------------------------------------
__global__ __launch_bounds__(256) void proj_res(const float* __restrict__ qkvbuf,
                                                const float* __restrict__ projw,
                                                const float* __restrict__ projb,
                                                float* __restrict__ x3,
                                                int shift) {
  __shared__ float ao[16 * 160];
  __shared__ int spos[16];
  int tid = threadIdx.x;
  int p0 = blockIdx.x * 16;
  if (tid < 16) spos[tid] = token_pos(p0 + tid, shift);
  for (int idx = tid; idx < 2560; idx += 256) {
    int t = idx / 160, ch = idx - t * 160;
    ao[idx] = qkvbuf[(long)(p0 + t) * 480 + ch];
  }
  __syncthreads();

  if (tid < 160) {
    int c = tid;
    float acc[16];
    float bc = projb[c];
#pragma unroll
    for (int t = 0; t < 16; t++) acc[t] = bc;
    for (int d = 0; d < 160; d++) {
      float wv = projw[d * 160 + c];
#pragma unroll
      for (int t = 0; t < 16; t++) acc[t] += ao[t * 160 + d] * wv;
    }
#pragma unroll
    for (int t = 0; t < 16; t++) {
      long a = (long)spos[t] * DIM + c;
      x3[a] = x3[a] + acc[t];
    }
  }
}

// ---------------------------------------------------------------------------
// pack_kernel: fp32 weight [K x ncols] -> bf16 MFMA-fragment-major layout
// dst[((ks*nfcnt + nf)*64 + lane)*8 + j] = src[(ks*32 + (lane>>4)*8 + j)*ncols + nf*16 + (lane&15)]
// 102400 elements (one matrix), grid 400 x 256.
// ---------------------------------------------------------------------------
__global__ __launch_bounds__(256) void pack_kernel(const float* __restrict__ src,
                                                   unsigned short* __restrict__ dst,
                                                   int nfcnt, int ncols) {
  int idx = blockIdx.x * 256 + threadIdx.x;  // < 102400
  int j = idx & 7;
  int lane = (idx >> 3) & 63;
  int t = idx >> 9;
  int nf = t % nfcnt, ks = t / nfcnt;
  int k = ks * 32 + (lane >> 4) * 8 + j;
  int n = nf * 16 + (lane & 15);
  dst[idx] = f2bf(src[k * ncols + n]);
}

// ---------------------------------------------------------------------------
// Kernel C: LN2 + MLP via bf16 MFMA. 32 tokens/block, 4 waves.
// fc1: waves split N (160 cols each); fc2: waves split K (160 each) + LDS reduce.
// ---------------------------------------------------------------------------
__global__ __launch_bounds__(256) void mlp_mfma(float* __restrict__ x3,
                                                const float* __restrict__ g,
                                                const float* __restrict__ bb,
                                                const unsigned short* __restrict__ w1f,
                                                const float* __restrict__ b1,
                                                const unsigned short* __restrict__ w2f,
                                                const float* __restrict__ b2) {
  __shared__ unsigned short lnv[32 * 168];   // bf16, row stride 168 (pad +8)
  __shared__ unsigned short h1s[32 * 648];   // bf16, row stride 648 (pad +8)
  __shared__ float redC[32 * 160];           // fc2 cross-wave reduction

  int tid = threadIdx.x;
  long p0 = (long)blockIdx.x * 32;

  // ---- LN2: 8 threads per token ----
  {
    int t = tid >> 3, sub = tid & 7;
    const float* row = x3 + (p0 + t) * 160 + sub * 20;
    float xv[20];
    float s1 = 0.f, s2 = 0.f;
#pragma unroll
    for (int m = 0; m < 20; m++) { float v = row[m]; xv[m] = v; s1 += v; s2 += v * v; }
#pragma unroll
    for (int m = 1; m < 8; m <<= 1) { s1 += __shfl_xor(s1, m); s2 += __shfl_xor(s2, m); }
    float mu = s1 * (1.f / 160.f);
    float rs = rsqrtf(s2 * (1.f / 160.f) - mu * mu + 1e-5f);
#pragma unroll
    for (int m = 0; m < 20; m++) {
      int c = sub * 20 + m;
      lnv[t * 168 + c] = f2bf((xv[m] - mu) * rs * g[c] + bb[c]);
    }
  }
  __syncthreads();

  int w = tid >> 6, lane = tid & 63, quad = lane >> 4, l16 = lane & 15;

  // ---- fc1: wave w -> cols [w*160, w*160+160) ----
  floatx4 acc[2][10];
#pragma unroll
  for (int mf = 0; mf < 2; mf++)
#pragma unroll
    for (int n = 0; n < 10; n++) acc[mf][n] = (floatx4){0.f, 0.f, 0.f, 0.f};

  for (int ks = 0; ks < 5; ks++) {
    short8 a0 = *(const short8*)&lnv[l16 * 168 + ks * 32 + quad * 8];
    short8 a1 = *(const short8*)&lnv[(16 + l16) * 168 + ks * 32 + quad * 8];
    const short8* bp = (const short8*)w1f + (ks * 40 + w * 10) * 64 + lane;
#pragma unroll
    for (int n = 0; n < 10; n++) {
      short8 bf = bp[n * 64];
      acc[0][n] = __builtin_amdgcn_mfma_f32_16x16x32_bf16(a0, bf, acc[0][n], 0, 0, 0);
      acc[1][n] = __builtin_amdgcn_mfma_f32_16x16x32_bf16(a1, bf, acc[1][n], 0, 0, 0);
    }
  }

  // fc1 epilogue: bias + gelu -> h1s (bf16)
#pragma unroll
  for (int mf = 0; mf < 2; mf++)
#pragma unroll
    for (int n = 0; n < 10; n++) {
      int col = w * 160 + n * 16 + l16;
      float bv = b1[col];
#pragma unroll
      for (int r = 0; r < 4; r++) {
        int tok = mf * 16 + quad * 4 + r;
        float a = acc[mf][n][r] + bv;
        float ge = 0.5f * a * (1.f + tanhf(0.7978845608028654f * (a + 0.044715f * a * a * a)));
        h1s[tok * 648 + col] = f2bf(ge);
      }
    }
  __syncthreads();

  // ---- fc2: wave w -> K slice [w*160, w*160+160) over all 160 cols ----
  floatx4 acc2[2][10];
#pragma unroll
  for (int mf = 0; mf < 2; mf++)
#pragma unroll
    for (int n = 0; n < 10; n++) acc2[mf][n] = (floatx4){0.f, 0.f, 0.f, 0.f};

  for (int i = tid; i < 5120; i += 256) redC[i] = 0.f;  // zero before barrier

  for (int s = 0; s < 5; s++) {
    int ksg = w * 5 + s;
    short8 a0 = *(const short8*)&h1s[l16 * 648 + ksg * 32 + quad * 8];
    short8 a1 = *(const short8*)&h1s[(16 + l16) * 648 + ksg * 32 + quad * 8];
    const short8* bp = (const short8*)w2f + (ksg * 10) * 64 + lane;
#pragma unroll
    for (int n = 0; n < 10; n++) {
      short8 bf = bp[n * 64];
      acc2[0][n] = __builtin_amdgcn_mfma_f32_16x16x32_bf16(a0, bf, acc2[0][n], 0, 0, 0);
      acc2[1][n] = __builtin_amdgcn_mfma_f32_16x16x32_bf16(a1, bf, acc2[1][n], 0, 0, 0);
    }
  }
  __syncthreads();  // redC zeroed + h1s reads done

#pragma unroll
  for (int mf = 0; mf < 2; mf++)
#pragma unroll
    for (int n = 0; n < 10; n++)
#pragma unroll
      for (int r = 0; r < 4; r++) {
        int tok = mf * 16 + quad * 4 + r, col = n * 16 + l16;
        atomicAdd(&redC[tok * 160 + col], acc2[mf][n][r]);
      }
  __syncthreads();

  // ---- residual + bias writeout ----
  for (int i = tid; i < 5120; i += 256) {
    int tok = i / 160, col = i - tok * 160;
    long a = p0 * 160 + i;
    x3[a] = x3[a] + redC[i] + b2[col];
  }
}

// ---------------------------------------------------------------------------
// Kernel D: y_planes[j][pos] = (x3 @ linw + linb)[pos][j], plane-major
// ---------------------------------------------------------------------------
__global__ __launch_bounds__(256) void lin_kernel(const float* __restrict__ x3,
                                                  const float* __restrict__ linw,
                                                  const float* __restrict__ linb,
                                                  float* __restrict__ yp) {
  __shared__ float xs[16 * 160];
  __shared__ float ys[144 * 17];
  int tid = threadIdx.x;
  long p0 = (long)blockIdx.x * 16;
  for (int idx = tid; idx < 2560; idx += 256) xs[idx] = x3[p0 * DIM + idx];
  __syncthreads();
  if (tid < 144) {
    int j = tid;
    float acc[16];
    float bj = linb[j];
#pragma unroll
    for (int t2 = 0; t2 < 16; t2++) acc[t2] = bj;
    for (int i = 0; i < 160; i++) {
      float wv = linw[i * 144 + j];
#pragma unroll
      for (int t2 = 0; t2 < 16; t2++) acc[t2] += xs[t2 * 160 + i] * wv;
    }
#pragma unroll
    for (int t2 = 0; t2 < 16; t2++) ys[j * 17 + t2] = acc[t2];
  }
  __syncthreads();
#pragma unroll
  for (int rep = 0; rep < 9; rep++) {
    int idx = tid + rep * 256;  // < 2304
    int j = idx >> 4, t2 = idx & 15;
    yp[(long)j * NPOS + p0 + t2] = ys[j * 17 + t2];
  }
}

// ---------------------------------------------------------------------------
// Kernel E: synthesis conv on plane-major y -> plane-major yt [16][NPOS]
// ---------------------------------------------------------------------------
__global__ __launch_bounds__(256) void syn_kernel(const float* __restrict__ yp,
                                                  const float* __restrict__ fsyn,
                                                  float* __restrict__ yt) {
  __shared__ float tileS[9 * 576];
  __shared__ float fsl[729];
  int tid = threadIdx.x;
  int blk = blockIdx.x;
  int b = blk / 784;
  int rem = blk - b * 784;
  int c = rem / 49;
  int tile = rem - c * 49;
  int y0 = (tile / 7) * 16, x0 = (tile % 7) * 16;

  for (int i = tid; i < 729; i += 256) fsl[i] = fsyn[i];
  for (int idx = tid; idx < 5184; idx += 256) {
    int k = idx / 576, r = idx - k * 576;
    int ly = r / 24, lx = r - ly * 24;
    int gy = y0 + ly - 4, gx = x0 + lx - 4;
    float v = 0.f;
    if (gy >= 0 && gy < HH && gx >= 0 && gx < WW)
      v = yp[(long)(k * 16 + c) * NPOS + (b * HH + gy) * WW + gx];
    tileS[idx] = v;
  }
  __syncthreads();

  int ty = tid >> 4, tx = tid & 15;
  float acc = 0.f;
  for (int k = 0; k < 9; k++) {
    const float* ts = &tileS[k * 576];
    const float* fk = &fsl[k * 81];
    for (int ky = 0; ky < 9; ky++)
#pragma unroll
      for (int kx = 0; kx < 9; kx++)
        acc += ts[(ty + ky) * 24 + (tx + kx)] * fk[ky * 9 + kx];
  }
  yt[(long)c * NPOS + (b * HH + (y0 + ty)) * WW + (x0 + tx)] = acc;
}

// ---------------------------------------------------------------------------
// Kernel F: final 1x1 conv from plane-major inputs -> out [B,16,H,W]
// ---------------------------------------------------------------------------
__global__ __launch_bounds__(256) void final_kernel(const float* __restrict__ yt,
                                                    const float* __restrict__ yp,
                                                    const float* __restrict__ convw,
                                                    const float* __restrict__ convb,
                                                    float* __restrict__ out) {
  long pos = (long)blockIdx.x * 256 + threadIdx.x;
  if (pos >= NPOS) return;
  int b = (int)(pos / (HH * WW));
  int hw = (int)(pos - (long)b * HH * WW);

  float acc[16];
#pragma unroll
  for (int co = 0; co < 16; co++) acc[co] = convb[co];
  for (int c = 0; c < 16; c++) {
    float v = yt[(long)c * NPOS + pos];
#pragma unroll
    for (int co = 0; co < 16; co++) acc[co] += v * convw[co * 160 + c];
  }
  for (int j = 0; j < 144; j++) {
    float v = yp[(long)j * NPOS + pos];
#pragma unroll
    for (int co = 0; co < 16; co++) acc[co] += v * convw[co * 160 + 16 + j];
  }
#pragma unroll
  for (int co = 0; co < 16; co++)
    out[(((long)b * 16 + co) * HH * WW) + hw] = acc[co];
}

// ---------------------------------------------------------------------------
extern "C" void kernel_launch(void* const* d_in, const int* in_sizes, int n_in,
                              void* d_out, int out_size, void* d_ws, size_t ws_size,
                              hipStream_t stream) {
  const float* x     = (const float*)d_in[0];
  const float* fana  = (const float*)d_in[1];
  const float* fsyn  = (const float*)d_in[2];
  const float* ln1g  = (const float*)d_in[3];
  const float* ln1b  = (const float*)d_in[4];
  const float* qkvw  = (const float*)d_in[5];
  const float* qkvb  = (const float*)d_in[6];
  const float* projw = (const float*)d_in[7];
  const float* projb = (const float*)d_in[8];
  const float* rpb   = (const float*)d_in[9];
  const float* ln2g  = (const float*)d_in[10];
  const float* ln2b  = (const float*)d_in[11];
  const float* w1    = (const float*)d_in[12];
  const float* b1    = (const float*)d_in[13];
  const float* w2    = (const float*)d_in[14];
  const float* b2    = (const float*)d_in[15];
  const float* linw  = (const float*)d_in[16];
  const float* linb  = (const float*)d_in[17];
  const float* convw = (const float*)d_in[18];
  const float* convb = (const float*)d_in[19];
  float* out = (float*)d_out;

  char* ws = (char*)d_ws;
  float* x3 = (float*)ws;                           // 64,225,280 B, live whole run
  char* region2 = ws + 64225280;                    // 192,675,840 B, time-shared:
  float* qkvbuf = (float*)region2;                  //   qkv/attn/proj phase
  unsigned short* w1f = (unsigned short*)region2;   //   mlp phase (qkvbuf dead)
  unsigned short* w2f = w1f + 102400;
  float* yp = (float*)region2;                      //   lin/syn/final phase
  float* yt = (float*)ws;                           //   aliases x3 (dead after lin)

  ana_kernel<<<BB * 49, 256, 0, stream>>>(x, fana, x3);
  for (int i = 0; i < 2; i++) {
    int shift = i ? (WIN / 2) : 0;
    qkv_kernel<<<NPOS / 16, 256, 0, stream>>>(x3, ln1g + i * 160, ln1b + i * 160,
                                              qkvw + i * 160 * 480, qkvb + i * 480,
                                              qkvbuf, shift);
    attn_core<<<BB * NWIN, 256, 0, stream>>>(qkvbuf, rpb + i * 169 * 5, shift);
    proj_res<<<NPOS / 16, 256, 0, stream>>>(qkvbuf, projw + i * 160 * 160,
                                            projb + i * 160, x3, shift);
    // repack this block's MLP weights into dead qkvbuf space (runs every call)
    pack_kernel<<<400, 256, 0, stream>>>(w1 + i * 102400, w1f, 40, 640);
    pack_kernel<<<400, 256, 0, stream>>>(w2 + i * 102400, w2f, 10, 160);
    mlp_mfma<<<NPOS / 32, 256, 0, stream>>>(x3, ln2g + i * 160, ln2b + i * 160,
                                            w1f, b1 + i * 640, w2f, b2 + i * 160);
  }
  lin_kernel<<<NPOS / 16, 256, 0, stream>>>(x3, linw, linb, yp);
  syn_kernel<<<BB * 16 * 49, 256, 0, stream>>>(yp, fsyn, yt);
  final_kernel<<<(NPOS + 255) / 256, 256, 0, stream>>>(yt, yp, convw, convb, out);
}

// Round 4
// 1677.989 us; speedup vs baseline: 23.9520x; 1.8007x over previous
//
#include <hip/hip_runtime.h>
#include <hip/hip_bf16.h>
#include <math.h>

#define BB 8
#define CC 16
#define HH 112
#define WW 112
#define KK 9
#define FS 9
#define WIN 7
#define DIM 160
#define HEADS 5
#define HDIM 32
#define MLPD 640
#define NWIN 256          // (112/7)^2
#define NPOS (BB*HH*WW)   // 100352

typedef __attribute__((ext_vector_type(8))) short short8;
typedef __attribute__((ext_vector_type(4))) float floatx4;

__device__ __forceinline__ unsigned short f2bf(float f) {
  union { float f; unsigned u; } v; v.f = f;
  unsigned r = v.u + 0x7fffu + ((v.u >> 16) & 1u);
  return (unsigned short)(r >> 16);
}
__device__ __forceinline__ float bf2f(unsigned short u) {
  union { unsigned u; float f; } v; v.u = ((unsigned)u) << 16;
  return v.f;
}
// gelu tanh-approx, exp-based (same formula as jax.nn.gelu, no libm tanh)
__device__ __forceinline__ float gelu_f(float a) {
  float z = 0.7978845608028654f * (a + 0.044715f * a * a * a);
  return a * __builtin_amdgcn_rcpf(1.f + __expf(-2.f * z));
}

// ---------------------------------------------------------------------------
// Kernel A: relu + analysis filter bank -> x3 [B,H,W,160] channels-last
// ---------------------------------------------------------------------------
__global__ __launch_bounds__(256) void ana_kernel(const float* __restrict__ x,
                                                  const float* __restrict__ fana,
                                                  float* __restrict__ x3) {
  __shared__ float tileS[16 * 576];  // 16 ch x 24x24
  __shared__ float fs[729];
  int tid = threadIdx.x;
  int blk = blockIdx.x;
  int b = blk / 49;
  int tile = blk - b * 49;
  int y0 = (tile / 7) * 16, x0 = (tile % 7) * 16;

  for (int i = tid; i < 729; i += 256) fs[i] = fana[i];
  for (int idx = tid; idx < 9216; idx += 256) {
    int c = idx / 576, r = idx - c * 576;
    int ly = r / 24, lx = r - ly * 24;
    int gy = y0 + ly - 4, gx = x0 + lx - 4;
    float v = 0.f;
    if (gy >= 0 && gy < HH && gx >= 0 && gx < WW)
      v = fmaxf(x[(((long)b * CC + c) * HH + gy) * WW + gx], 0.f);
    tileS[idx] = v;
  }
  __syncthreads();

  int ty = tid >> 4, tx = tid & 15;
  long obase = (((long)b * HH + (y0 + ty)) * WW + (x0 + tx)) * DIM;
  for (int c = 0; c < 16; c++) {
    float acc[9];
#pragma unroll
    for (int k = 0; k < 9; k++) acc[k] = 0.f;
    const float* ts = &tileS[c * 576];
    for (int ky = 0; ky < 9; ky++)
      for (int kx = 0; kx < 9; kx++) {
        float v = ts[(ty + ky) * 24 + (tx + kx)];
#pragma unroll
        for (int k = 0; k < 9; k++) acc[k] += v * fs[k * 81 + ky * 9 + kx];
      }
#pragma unroll
    for (int k = 0; k < 9; k++) x3[obase + k * 16 + c] = acc[k];
    x3[obase + 144 + c] = ts[(ty + 4) * 24 + (tx + 4)];  // relu skip
  }
}

// ---------------------------------------------------------------------------
// token_pos: window-ordered flat token p -> source position in [B,H,W]
// ---------------------------------------------------------------------------
__device__ __forceinline__ int token_pos(int p, int shift) {
  int w = p / 49;
  int t = p - w * 49;
  int b = w >> 8;
  int wid = w & 255;
  int wi = wid >> 4, wj = wid & 15;
  int iy = t / 7, ix = t - (t / 7) * 7;
  int hy = (wi * 7 + iy + shift) % HH;
  int wx = (wj * 7 + ix + shift) % WW;
  return (b * HH + hy) * WW + wx;
}

// ---------------------------------------------------------------------------
// pack_kernel: fp32 weight [K x ncols] -> bf16 MFMA B-fragment-major layout
// dst[((ks*nfcnt+nf)*64+lane)*8+j] = src[(ks*32+(lane>>4)*8+j)*ncols + nf*16+(lane&15)]
// ---------------------------------------------------------------------------
__global__ __launch_bounds__(256) void pack_kernel(const float* __restrict__ src,
                                                   unsigned short* __restrict__ dst,
                                                   int nfcnt, int ncols, int nelems) {
  int idx = blockIdx.x * 256 + threadIdx.x;
  if (idx >= nelems) return;
  int j = idx & 7;
  int lane = (idx >> 3) & 63;
  int t = idx >> 9;
  int nf = t % nfcnt, ks = t / nfcnt;
  int k = ks * 32 + (lane >> 4) * 8 + j;
  int n = nf * 16 + (lane & 15);
  dst[idx] = f2bf(src[k * ncols + n]);
}

// ---------------------------------------------------------------------------
// Kernel B1: LN1 + qkv GEMM via bf16 MFMA. 64 tokens/block (window-ordered),
// 4 waves, wave = one 16-token M-frag, all 30 N-frags (2 halves of 15).
// Output: qkvbuf bf16 [NPOS x 480].
// ---------------------------------------------------------------------------
__global__ __launch_bounds__(256) void qkv_mfma(const float* __restrict__ x3,
                                                const float* __restrict__ g,
                                                const float* __restrict__ bb,
                                                const unsigned short* __restrict__ qkvf,
                                                const float* __restrict__ qkvb,
                                                unsigned short* __restrict__ qkvbuf,
                                                int shift) {
  __shared__ unsigned short lnv[64 * 168];  // bf16, row stride 168

  int tid = threadIdx.x;
  int p0 = blockIdx.x * 64;

  // ---- LN1: 4 threads per token, 40 elems each ----
  {
    int t = tid >> 2, sub = tid & 3;
    int pos = token_pos(p0 + t, shift);
    const float* row = x3 + (long)pos * 160 + sub * 40;
    float xv[40];
    float s1 = 0.f, s2 = 0.f;
#pragma unroll
    for (int m = 0; m < 40; m++) { float v = row[m]; xv[m] = v; s1 += v; s2 += v * v; }
    s1 += __shfl_xor(s1, 1); s2 += __shfl_xor(s2, 1);
    s1 += __shfl_xor(s1, 2); s2 += __shfl_xor(s2, 2);
    float mu = s1 * (1.f / 160.f);
    float rs = rsqrtf(s2 * (1.f / 160.f) - mu * mu + 1e-5f);
#pragma unroll
    for (int m = 0; m < 40; m++) {
      int c = sub * 40 + m;
      lnv[t * 168 + c] = f2bf((xv[m] - mu) * rs * g[c] + bb[c]);
    }
  }
  __syncthreads();

  int w = tid >> 6, lane = tid & 63, quad = lane >> 4, l16 = lane & 15;

#pragma unroll
  for (int half = 0; half < 2; half++) {
    floatx4 acc[15];
#pragma unroll
    for (int n = 0; n < 15; n++) acc[n] = (floatx4){0.f, 0.f, 0.f, 0.f};
    for (int ks = 0; ks < 5; ks++) {
      short8 a = *(const short8*)&lnv[(w * 16 + l16) * 168 + ks * 32 + quad * 8];
      const short8* bp = (const short8*)qkvf + (ks * 30 + half * 15) * 64 + lane;
#pragma unroll
      for (int n = 0; n < 15; n++)
        acc[n] = __builtin_amdgcn_mfma_f32_16x16x32_bf16(a, bp[n * 64], acc[n], 0, 0, 0);
    }
#pragma unroll
    for (int n = 0; n < 15; n++) {
      int col = (half * 15 + n) * 16 + l16;
      float bv = qkvb[col];
#pragma unroll
      for (int r = 0; r < 4; r++) {
        int tok = p0 + w * 16 + quad * 4 + r;
        qkvbuf[(long)tok * 480 + col] = f2bf(acc[n][r] + bv);
      }
    }
  }
}

// ---------------------------------------------------------------------------
// Kernel B2: per-window attention core (bf16 in/out, fp32 math)
// ---------------------------------------------------------------------------
__global__ __launch_bounds__(256) void attn_core(unsigned short* __restrict__ qkvbuf,
                                                 const float* __restrict__ rpb,
                                                 int shift) {
  __shared__ float qs[49 * 36], ksh[49 * 36], vsh[49 * 36];  // stride 36: 16B-aligned rows
  __shared__ float pb[49 * 49];

  int tid = threadIdx.x;
  int w = blockIdx.x;
  int wid = w & 255;
  int wi = wid >> 4, wj = wid & 15;
  long base = (long)w * 49 * 480;

  for (int h = 0; h < HEADS; h++) {
    for (int idx = tid; idx < 4704; idx += 256) {
      int m = idx / 1568;
      int r = idx - m * 1568;
      int t = r >> 5, d = r & 31;
      float v = bf2f(qkvbuf[base + (long)t * 480 + m * 160 + h * 32 + d]);
      float* dst = (m == 0) ? qs : (m == 1) ? ksh : vsh;
      dst[t * 36 + d] = v;
    }
    __syncthreads();

    // scores: thread (i, jg) with q row cached in registers
    if (tid < 245) {
      int i = tid / 5, jg = tid - (tid / 5) * 5;
      int j0 = jg * 10, jn = (jg == 4) ? 9 : 10;
      float4 qr[8];
#pragma unroll
      for (int d4 = 0; d4 < 8; d4++) qr[d4] = *(const float4*)&qs[i * 36 + d4 * 4];
      int iy = i / 7, ix = i - iy * 7;
      int hri = wi * 7 + iy, wri = wj * 7 + ix;
      int ai = hri < 105 ? 0 : (hri < 109 ? 1 : 2);
      int bi = wri < 105 ? 0 : (wri < 109 ? 1 : 2);
      for (int jj = 0; jj < jn; jj++) {
        int j = j0 + jj;
        float s = 0.f;
#pragma unroll
        for (int d4 = 0; d4 < 8; d4++) {
          float4 kr = *(const float4*)&ksh[j * 36 + d4 * 4];
          s += qr[d4].x * kr.x + qr[d4].y * kr.y + qr[d4].z * kr.z + qr[d4].w * kr.w;
        }
        s *= 0.17677669529663687f;
        int jy = j / 7, jx = j - jy * 7;
        int rel = (iy - jy + 6) * 13 + (ix - jx + 6);
        s += rpb[rel * 5 + h];
        if (shift) {
          int hrj = wi * 7 + jy, wrj = wj * 7 + jx;
          int aj = hrj < 105 ? 0 : (hrj < 109 ? 1 : 2);
          int bj2 = wrj < 105 ? 0 : (wrj < 109 ? 1 : 2);
          if (ai != aj || bi != bj2) s -= 100.f;
        }
        pb[i * 49 + j] = s;
      }
    }
    __syncthreads();

    if (tid < 49) {
      float m = -1e30f;
      for (int j = 0; j < 49; j++) m = fmaxf(m, pb[tid * 49 + j]);
      float sum = 0.f;
      for (int j = 0; j < 49; j++) {
        float e = __expf(pb[tid * 49 + j] - m);
        pb[tid * 49 + j] = e;
        sum += e;
      }
      float inv = 1.f / sum;
      for (int j = 0; j < 49; j++) pb[tid * 49 + j] *= inv;
    }
    __syncthreads();

    // out = P @ V -> q-slot cols (bf16); pb read is lane-broadcast
    for (int o = tid; o < 1568; o += 256) {
      int i = o >> 5, d = o & 31;
      float acc = 0.f;
      for (int j = 0; j < 49; j++) acc += pb[i * 49 + j] * vsh[j * 36 + d];
      qkvbuf[base + (long)i * 480 + h * 32 + d] = f2bf(acc);
    }
    __syncthreads();
  }
}

// ---------------------------------------------------------------------------
// Kernel B3: proj via bf16 MFMA + residual scatter-add. 64 tokens/block.
// ---------------------------------------------------------------------------
__global__ __launch_bounds__(256) void proj_mfma(const unsigned short* __restrict__ qkvbuf,
                                                 const unsigned short* __restrict__ projf,
                                                 const float* __restrict__ projb,
                                                 float* __restrict__ x3,
                                                 int shift) {
  __shared__ unsigned short ao[64 * 168];
  __shared__ int spos[64];
  int tid = threadIdx.x;
  int p0 = blockIdx.x * 64;
  if (tid < 64) spos[tid] = token_pos(p0 + tid, shift);
  for (int idx = tid; idx < 10240; idx += 256) {
    int t = idx / 160, ch = idx - t * 160;
    ao[t * 168 + ch] = qkvbuf[(long)(p0 + t) * 480 + ch];
  }
  __syncthreads();

  int w = tid >> 6, lane = tid & 63, quad = lane >> 4, l16 = lane & 15;
  floatx4 acc[10];
#pragma unroll
  for (int n = 0; n < 10; n++) acc[n] = (floatx4){0.f, 0.f, 0.f, 0.f};
  for (int ks = 0; ks < 5; ks++) {
    short8 a = *(const short8*)&ao[(w * 16 + l16) * 168 + ks * 32 + quad * 8];
    const short8* bp = (const short8*)projf + (ks * 10) * 64 + lane;
#pragma unroll
    for (int n = 0; n < 10; n++)
      acc[n] = __builtin_amdgcn_mfma_f32_16x16x32_bf16(a, bp[n * 64], acc[n], 0, 0, 0);
  }
#pragma unroll
  for (int n = 0; n < 10; n++) {
    int col = n * 16 + l16;
    float bv = projb[col];
#pragma unroll
    for (int r = 0; r < 4; r++) {
      int tl = w * 16 + quad * 4 + r;
      long a = (long)spos[tl] * DIM + col;
      x3[a] = x3[a] + acc[n][r] + bv;
    }
  }
}

// ---------------------------------------------------------------------------
// Kernel C: LN2 + MLP via bf16 MFMA. 32 tokens/block, 4 waves.
// fc1: waves split N (160 cols each). fc2: waves split (M x N), full K, no reduce.
// ---------------------------------------------------------------------------
__global__ __launch_bounds__(256) void mlp_mfma(float* __restrict__ x3,
                                                const float* __restrict__ g,
                                                const float* __restrict__ bb,
                                                const unsigned short* __restrict__ w1f,
                                                const float* __restrict__ b1,
                                                const unsigned short* __restrict__ w2f,
                                                const float* __restrict__ b2) {
  __shared__ unsigned short lnv[32 * 168];   // bf16, row stride 168
  __shared__ unsigned short h1s[32 * 648];   // bf16, row stride 648

  int tid = threadIdx.x;
  long p0 = (long)blockIdx.x * 32;

  // ---- LN2: 8 threads per token ----
  {
    int t = tid >> 3, sub = tid & 7;
    const float* row = x3 + (p0 + t) * 160 + sub * 20;
    float xv[20];
    float s1 = 0.f, s2 = 0.f;
#pragma unroll
    for (int m = 0; m < 20; m++) { float v = row[m]; xv[m] = v; s1 += v; s2 += v * v; }
#pragma unroll
    for (int m = 1; m < 8; m <<= 1) { s1 += __shfl_xor(s1, m); s2 += __shfl_xor(s2, m); }
    float mu = s1 * (1.f / 160.f);
    float rs = rsqrtf(s2 * (1.f / 160.f) - mu * mu + 1e-5f);
#pragma unroll
    for (int m = 0; m < 20; m++) {
      int c = sub * 20 + m;
      lnv[t * 168 + c] = f2bf((xv[m] - mu) * rs * g[c] + bb[c]);
    }
  }
  __syncthreads();

  int w = tid >> 6, lane = tid & 63, quad = lane >> 4, l16 = lane & 15;

  // ---- fc1: wave w -> cols [w*160, w*160+160) ----
  floatx4 acc[2][10];
#pragma unroll
  for (int mf = 0; mf < 2; mf++)
#pragma unroll
    for (int n = 0; n < 10; n++) acc[mf][n] = (floatx4){0.f, 0.f, 0.f, 0.f};

  for (int ks = 0; ks < 5; ks++) {
    short8 a0 = *(const short8*)&lnv[l16 * 168 + ks * 32 + quad * 8];
    short8 a1 = *(const short8*)&lnv[(16 + l16) * 168 + ks * 32 + quad * 8];
    const short8* bp = (const short8*)w1f + (ks * 40 + w * 10) * 64 + lane;
#pragma unroll
    for (int n = 0; n < 10; n++) {
      short8 bf = bp[n * 64];
      acc[0][n] = __builtin_amdgcn_mfma_f32_16x16x32_bf16(a0, bf, acc[0][n], 0, 0, 0);
      acc[1][n] = __builtin_amdgcn_mfma_f32_16x16x32_bf16(a1, bf, acc[1][n], 0, 0, 0);
    }
  }

  // fc1 epilogue: bias + gelu -> h1s (bf16)
#pragma unroll
  for (int mf = 0; mf < 2; mf++)
#pragma unroll
    for (int n = 0; n < 10; n++) {
      int col = w * 160 + n * 16 + l16;
      float bv = b1[col];
#pragma unroll
      for (int r = 0; r < 4; r++) {
        int tok = mf * 16 + quad * 4 + r;
        h1s[tok * 648 + col] = f2bf(gelu_f(acc[mf][n][r] + bv));
      }
    }
  __syncthreads();

  // ---- fc2: wave w -> M-frag (w&1), N-frags [(w>>1)*5 .. +5), full K ----
  int mf = w & 1, nb = (w >> 1) * 5;
  floatx4 acc2[5];
#pragma unroll
  for (int n = 0; n < 5; n++) acc2[n] = (floatx4){0.f, 0.f, 0.f, 0.f};
  for (int ks = 0; ks < 20; ks++) {
    short8 a = *(const short8*)&h1s[(mf * 16 + l16) * 648 + ks * 32 + quad * 8];
    const short8* bp = (const short8*)w2f + (ks * 10 + nb) * 64 + lane;
#pragma unroll
    for (int n = 0; n < 5; n++)
      acc2[n] = __builtin_amdgcn_mfma_f32_16x16x32_bf16(a, bp[n * 64], acc2[n], 0, 0, 0);
  }

  // residual + bias writeout (each element owned by exactly one lane)
#pragma unroll
  for (int n = 0; n < 5; n++) {
    int col = (nb + n) * 16 + l16;
    float bv = b2[col];
#pragma unroll
    for (int r = 0; r < 4; r++) {
      int tok = mf * 16 + quad * 4 + r;
      long a = (p0 + tok) * 160 + col;
      x3[a] = x3[a] + acc2[n][r] + bv;
    }
  }
}

// ---------------------------------------------------------------------------
// Kernel D: y_planes[j][pos] = (x3 @ linw + linb)[pos][j], plane-major
// ---------------------------------------------------------------------------
__global__ __launch_bounds__(256) void lin_kernel(const float* __restrict__ x3,
                                                  const float* __restrict__ linw,
                                                  const float* __restrict__ linb,
                                                  float* __restrict__ yp) {
  __shared__ float xs[16 * 160];
  __shared__ float ys[144 * 17];
  int tid = threadIdx.x;
  long p0 = (long)blockIdx.x * 16;
  for (int idx = tid; idx < 2560; idx += 256) xs[idx] = x3[p0 * DIM + idx];
  __syncthreads();
  if (tid < 144) {
    int j = tid;
    float acc[16];
    float bj = linb[j];
#pragma unroll
    for (int t2 = 0; t2 < 16; t2++) acc[t2] = bj;
    for (int i = 0; i < 160; i++) {
      float wv = linw[i * 144 + j];
#pragma unroll
      for (int t2 = 0; t2 < 16; t2++) acc[t2] += xs[t2 * 160 + i] * wv;
    }
#pragma unroll
    for (int t2 = 0; t2 < 16; t2++) ys[j * 17 + t2] = acc[t2];
  }
  __syncthreads();
#pragma unroll
  for (int rep = 0; rep < 9; rep++) {
    int idx = tid + rep * 256;  // < 2304
    int j = idx >> 4, t2 = idx & 15;
    yp[(long)j * NPOS + p0 + t2] = ys[j * 17 + t2];
  }
}

// ---------------------------------------------------------------------------
// Kernel E: synthesis conv on plane-major y -> plane-major yt [16][NPOS]
// ---------------------------------------------------------------------------
__global__ __launch_bounds__(256) void syn_kernel(const float* __restrict__ yp,
                                                  const float* __restrict__ fsyn,
                                                  float* __restrict__ yt) {
  __shared__ float tileS[9 * 576];
  __shared__ float fsl[729];
  int tid = threadIdx.x;
  int blk = blockIdx.x;
  int b = blk / 784;
  int rem = blk - b * 784;
  int c = rem / 49;
  int tile = rem - c * 49;
  int y0 = (tile / 7) * 16, x0 = (tile % 7) * 16;

  for (int i = tid; i < 729; i += 256) fsl[i] = fsyn[i];
  for (int idx = tid; idx < 5184; idx += 256) {
    int k = idx / 576, r = idx - k * 576;
    int ly = r / 24, lx = r - ly * 24;
    int gy = y0 + ly - 4, gx = x0 + lx - 4;
    float v = 0.f;
    if (gy >= 0 && gy < HH && gx >= 0 && gx < WW)
      v = yp[(long)(k * 16 + c) * NPOS + (b * HH + gy) * WW + gx];
    tileS[idx] = v;
  }
  __syncthreads();

  int ty = tid >> 4, tx = tid & 15;
  float acc = 0.f;
  for (int k = 0; k < 9; k++) {
    const float* ts = &tileS[k * 576];
    const float* fk = &fsl[k * 81];
    for (int ky = 0; ky < 9; ky++)
#pragma unroll
      for (int kx = 0; kx < 9; kx++)
        acc += ts[(ty + ky) * 24 + (tx + kx)] * fk[ky * 9 + kx];
  }
  yt[(long)c * NPOS + (b * HH + (y0 + ty)) * WW + (x0 + tx)] = acc;
}

// ---------------------------------------------------------------------------
// Kernel F: final 1x1 conv from plane-major inputs -> out [B,16,H,W]
// ---------------------------------------------------------------------------
__global__ __launch_bounds__(256) void final_kernel(const float* __restrict__ yt,
                                                    const float* __restrict__ yp,
                                                    const float* __restrict__ convw,
                                                    const float* __restrict__ convb,
                                                    float* __restrict__ out) {
  long pos = (long)blockIdx.x * 256 + threadIdx.x;
  if (pos >= NPOS) return;
  int b = (int)(pos / (HH * WW));
  int hw = (int)(pos - (long)b * HH * WW);

  float acc[16];
#pragma unroll
  for (int co = 0; co < 16; co++) acc[co] = convb[co];
  for (int c = 0; c < 16; c++) {
    float v = yt[(long)c * NPOS + pos];
#pragma unroll
    for (int co = 0; co < 16; co++) acc[co] += v * convw[co * 160 + c];
  }
  for (int j = 0; j < 144; j++) {
    float v = yp[(long)j * NPOS + pos];
#pragma unroll
    for (int co = 0; co < 16; co++) acc[co] += v * convw[co * 160 + 16 + j];
  }
#pragma unroll
  for (int co = 0; co < 16; co++)
    out[(((long)b * 16 + co) * HH * WW) + hw] = acc[co];
}

// ---------------------------------------------------------------------------
extern "C" void kernel_launch(void* const* d_in, const int* in_sizes, int n_in,
                              void* d_out, int out_size, void* d_ws, size_t ws_size,
                              hipStream_t stream) {
  const float* x     = (const float*)d_in[0];
  const float* fana  = (const float*)d_in[1];
  const float* fsyn  = (const float*)d_in[2];
  const float* ln1g  = (const float*)d_in[3];
  const float* ln1b  = (const float*)d_in[4];
  const float* qkvw  = (const float*)d_in[5];
  const float* qkvb  = (const float*)d_in[6];
  const float* projw = (const float*)d_in[7];
  const float* projb = (const float*)d_in[8];
  const float* rpb   = (const float*)d_in[9];
  const float* ln2g  = (const float*)d_in[10];
  const float* ln2b  = (const float*)d_in[11];
  const float* w1    = (const float*)d_in[12];
  const float* b1    = (const float*)d_in[13];
  const float* w2    = (const float*)d_in[14];
  const float* b2    = (const float*)d_in[15];
  const float* linw  = (const float*)d_in[16];
  const float* linb  = (const float*)d_in[17];
  const float* convw = (const float*)d_in[18];
  const float* convb = (const float*)d_in[19];
  float* out = (float*)d_out;

  char* ws = (char*)d_ws;
  float* x3 = (float*)ws;                           // 64,225,280 B, live whole run
  char* region2 = ws + 64225280;                    // time-shared:
  unsigned short* qkvbuf = (unsigned short*)region2;           // bf16 [NPOS x 480] = 96,337,920 B
  unsigned short* packs  = (unsigned short*)(region2 + 96337920);
  unsigned short* qkvf = packs;                     // 76800 ush
  unsigned short* projf = packs + 76800;            // 25600 ush
  unsigned short* w1f   = packs + 102400;           // 102400 ush
  unsigned short* w2f   = packs + 204800;           // 102400 ush
  float* yp = (float*)region2;                      // lin/syn/final phase (57.8 MB)
  float* yt = (float*)ws;                           // aliases x3 (dead after lin)

  ana_kernel<<<BB * 49, 256, 0, stream>>>(x, fana, x3);
  for (int i = 0; i < 2; i++) {
    int shift = i ? (WIN / 2) : 0;
    pack_kernel<<<300, 256, 0, stream>>>(qkvw + i * 76800, qkvf, 30, 480, 76800);
    pack_kernel<<<100, 256, 0, stream>>>(projw + i * 25600, projf, 10, 160, 25600);
    pack_kernel<<<400, 256, 0, stream>>>(w1 + i * 102400, w1f, 40, 640, 102400);
    pack_kernel<<<400, 256, 0, stream>>>(w2 + i * 102400, w2f, 10, 160, 102400);
    qkv_mfma<<<NPOS / 64, 256, 0, stream>>>(x3, ln1g + i * 160, ln1b + i * 160,
                                            qkvf, qkvb + i * 480, qkvbuf, shift);
    attn_core<<<BB * NWIN, 256, 0, stream>>>(qkvbuf, rpb + i * 169 * 5, shift);
    proj_mfma<<<NPOS / 64, 256, 0, stream>>>(qkvbuf, projf, projb + i * 160, x3, shift);
    mlp_mfma<<<NPOS / 32, 256, 0, stream>>>(x3, ln2g + i * 160, ln2b + i * 160,
                                            w1f, b1 + i * 640, w2f, b2 + i * 160);
  }
  lin_kernel<<<NPOS / 16, 256, 0, stream>>>(x3, linw, linb, yp);
  syn_kernel<<<BB * 16 * 49, 256, 0, stream>>>(yp, fsyn, yt);
  final_kernel<<<(NPOS + 255) / 256, 256, 0, stream>>>(yt, yp, convw, convb, out);
}

// Round 5
// 1552.129 us; speedup vs baseline: 25.8942x; 1.0811x over previous
//
#include <hip/hip_runtime.h>
#include <hip/hip_bf16.h>
#include <math.h>

#define BB 8
#define CC 16
#define HH 112
#define WW 112
#define KK 9
#define FS 9
#define WIN 7
#define DIM 160
#define HEADS 5
#define HDIM 32
#define MLPD 640
#define NWIN 256          // (112/7)^2
#define NPOS (BB*HH*WW)   // 100352

typedef __attribute__((ext_vector_type(8))) short short8;
typedef __attribute__((ext_vector_type(4))) float floatx4;

__device__ __forceinline__ unsigned short f2bf(float f) {
  union { float f; unsigned u; } v; v.f = f;
  unsigned r = v.u + 0x7fffu + ((v.u >> 16) & 1u);
  return (unsigned short)(r >> 16);
}
__device__ __forceinline__ float bf2f(unsigned short u) {
  union { unsigned u; float f; } v; v.u = ((unsigned)u) << 16;
  return v.f;
}
// gelu tanh-approx, exp-based (same formula as jax.nn.gelu, no libm tanh)
__device__ __forceinline__ float gelu_f(float a) {
  float z = 0.7978845608028654f * (a + 0.044715f * a * a * a);
  return a * __builtin_amdgcn_rcpf(1.f + __expf(-2.f * z));
}
// x3 uses internal channel order ch' = c*10 + k (k=0..8 subbands, 9 = relu skip).
// orig_ch maps internal -> reference channel (k*16+c for k<9, 144+c for k=9).
__device__ __forceinline__ int orig_ch(int ch) {
  int c = ch / 10, k = ch - c * 10;
  return (k < 9) ? k * 16 + c : 144 + c;
}

// ---------------------------------------------------------------------------
// Kernel A: relu + analysis filter bank -> x3 [B,H,W,160] (permuted channels)
// Per (pos,c): 10 contiguous floats -> 5 aligned float2 stores (full-line writes)
// ---------------------------------------------------------------------------
__global__ __launch_bounds__(256) void ana_kernel(const float* __restrict__ x,
                                                  const float* __restrict__ fana,
                                                  float* __restrict__ x3) {
  __shared__ float tileS[16 * 576];  // 16 ch x 24x24
  __shared__ float fs[729];
  int tid = threadIdx.x;
  int blk = blockIdx.x;
  int b = blk / 49;
  int tile = blk - b * 49;
  int y0 = (tile / 7) * 16, x0 = (tile % 7) * 16;

  for (int i = tid; i < 729; i += 256) fs[i] = fana[i];
  for (int idx = tid; idx < 9216; idx += 256) {
    int c = idx / 576, r = idx - c * 576;
    int ly = r / 24, lx = r - ly * 24;
    int gy = y0 + ly - 4, gx = x0 + lx - 4;
    float v = 0.f;
    if (gy >= 0 && gy < HH && gx >= 0 && gx < WW)
      v = fmaxf(x[(((long)b * CC + c) * HH + gy) * WW + gx], 0.f);
    tileS[idx] = v;
  }
  __syncthreads();

  int ty = tid >> 4, tx = tid & 15;
  long obase = (((long)b * HH + (y0 + ty)) * WW + (x0 + tx)) * DIM;
  for (int c = 0; c < 16; c++) {
    float acc[9];
#pragma unroll
    for (int k = 0; k < 9; k++) acc[k] = 0.f;
    const float* ts = &tileS[c * 576];
    for (int ky = 0; ky < 9; ky++)
      for (int kx = 0; kx < 9; kx++) {
        float v = ts[(ty + ky) * 24 + (tx + kx)];
#pragma unroll
        for (int k = 0; k < 9; k++) acc[k] += v * fs[k * 81 + ky * 9 + kx];
      }
    float skip = ts[(ty + 4) * 24 + (tx + 4)];
    float2* dst = (float2*)&x3[obase + c * 10];
    dst[0] = make_float2(acc[0], acc[1]);
    dst[1] = make_float2(acc[2], acc[3]);
    dst[2] = make_float2(acc[4], acc[5]);
    dst[3] = make_float2(acc[6], acc[7]);
    dst[4] = make_float2(acc[8], skip);
  }
}

// ---------------------------------------------------------------------------
// token_pos: window-ordered flat token p -> source position in [B,H,W]
// ---------------------------------------------------------------------------
__device__ __forceinline__ int token_pos(int p, int shift) {
  int w = p / 49;
  int t = p - w * 49;
  int b = w >> 8;
  int wid = w & 255;
  int wi = wid >> 4, wj = wid & 15;
  int iy = t / 7, ix = t - (t / 7) * 7;
  int hy = (wi * 7 + iy + shift) % HH;
  int wx = (wj * 7 + ix + shift) % WW;
  return (b * HH + hy) * WW + wx;
}

// ---------------------------------------------------------------------------
// pack_kernel: fp32 weight [K x ncols] -> bf16 MFMA B-fragment-major layout.
// permK/permN: map the K-row / N-col index through orig_ch (x3-channel dims).
// ---------------------------------------------------------------------------
__global__ __launch_bounds__(256) void pack_kernel(const float* __restrict__ src,
                                                   unsigned short* __restrict__ dst,
                                                   int nfcnt, int ncols, int nelems,
                                                   int permK, int permN) {
  int idx = blockIdx.x * 256 + threadIdx.x;
  if (idx >= nelems) return;
  int j = idx & 7;
  int lane = (idx >> 3) & 63;
  int t = idx >> 9;
  int nf = t % nfcnt, ks = t / nfcnt;
  int k = ks * 32 + (lane >> 4) * 8 + j;
  int n = nf * 16 + (lane & 15);
  if (permK) k = orig_ch(k);
  if (permN) n = orig_ch(n);
  dst[idx] = f2bf(src[k * ncols + n]);
}

// ---------------------------------------------------------------------------
// Kernel B1: LN1 + qkv GEMM via bf16 MFMA. 64 tokens/block (window-ordered).
// x3 channels are permuted; qkvf rows packed with matching permutation.
// ---------------------------------------------------------------------------
__global__ __launch_bounds__(256) void qkv_mfma(const float* __restrict__ x3,
                                                const float* __restrict__ g,
                                                const float* __restrict__ bb,
                                                const unsigned short* __restrict__ qkvf,
                                                const float* __restrict__ qkvb,
                                                unsigned short* __restrict__ qkvbuf,
                                                int shift) {
  __shared__ unsigned short lnv[64 * 168];  // bf16, row stride 168

  int tid = threadIdx.x;
  int p0 = blockIdx.x * 64;

  // ---- LN1: 4 threads per token, 40 elems each (permuted channel space) ----
  {
    int t = tid >> 2, sub = tid & 3;
    int pos = token_pos(p0 + t, shift);
    const float* row = x3 + (long)pos * 160 + sub * 40;
    float xv[40];
    float s1 = 0.f, s2 = 0.f;
#pragma unroll
    for (int m = 0; m < 40; m++) { float v = row[m]; xv[m] = v; s1 += v; s2 += v * v; }
    s1 += __shfl_xor(s1, 1); s2 += __shfl_xor(s2, 1);
    s1 += __shfl_xor(s1, 2); s2 += __shfl_xor(s2, 2);
    float mu = s1 * (1.f / 160.f);
    float rs = rsqrtf(s2 * (1.f / 160.f) - mu * mu + 1e-5f);
#pragma unroll
    for (int m = 0; m < 40; m++) {
      int c = sub * 40 + m;
      int oc = orig_ch(c);
      lnv[t * 168 + c] = f2bf((xv[m] - mu) * rs * g[oc] + bb[oc]);
    }
  }
  __syncthreads();

  int w = tid >> 6, lane = tid & 63, quad = lane >> 4, l16 = lane & 15;

#pragma unroll
  for (int half = 0; half < 2; half++) {
    floatx4 acc[15];
#pragma unroll
    for (int n = 0; n < 15; n++) acc[n] = (floatx4){0.f, 0.f, 0.f, 0.f};
    for (int ks = 0; ks < 5; ks++) {
      short8 a = *(const short8*)&lnv[(w * 16 + l16) * 168 + ks * 32 + quad * 8];
      const short8* bp = (const short8*)qkvf + (ks * 30 + half * 15) * 64 + lane;
#pragma unroll
      for (int n = 0; n < 15; n++)
        acc[n] = __builtin_amdgcn_mfma_f32_16x16x32_bf16(a, bp[n * 64], acc[n], 0, 0, 0);
    }
#pragma unroll
    for (int n = 0; n < 15; n++) {
      int col = (half * 15 + n) * 16 + l16;
      float bv = qkvb[col];
#pragma unroll
      for (int r = 0; r < 4; r++) {
        int tok = p0 + w * 16 + quad * 4 + r;
        qkvbuf[(long)tok * 480 + col] = f2bf(acc[n][r] + bv);
      }
    }
  }
}

// ---------------------------------------------------------------------------
// Kernel B2: attention core, one block per (window, head), 128 threads.
// ---------------------------------------------------------------------------
__global__ __launch_bounds__(128) void attn_core(unsigned short* __restrict__ qkvbuf,
                                                 const float* __restrict__ rpb,
                                                 int shift) {
  __shared__ float qs[49 * 36], ksh[49 * 36], vsh[49 * 36];  // 16B-aligned rows
  __shared__ float pb[49 * 49];
  __shared__ float bias_s[169];

  int tid = threadIdx.x;
  int bid = blockIdx.x;
  int w = bid / 5, h = bid - (bid / 5) * 5;
  int wid = w & 255;
  int wi = wid >> 4, wj = wid & 15;
  long base = (long)w * 49 * 480;

  for (int i = tid; i < 169; i += 128) bias_s[i] = rpb[i * 5 + h];

  // load q,k,v [49,32] for this head, vectorized ushort4 -> float4
  for (int idx = tid; idx < 1176; idx += 128) {
    int m = idx / 392, r = idx - m * 392;
    int t = r >> 3, d4 = r & 7;
    ushort4 u = *(const ushort4*)&qkvbuf[base + (long)t * 480 + m * 160 + h * 32 + d4 * 4];
    float4 f = make_float4(bf2f(u.x), bf2f(u.y), bf2f(u.z), bf2f(u.w));
    float* dst = (m == 0) ? qs : (m == 1) ? ksh : vsh;
    *(float4*)&dst[t * 36 + d4 * 4] = f;
  }
  __syncthreads();

  // scores: thread (row i, half) with q-row cached in registers
  if (tid < 98) {
    int i = tid >> 1, halfj = tid & 1;
    int j0 = halfj * 25, jn = halfj ? 24 : 25;
    float4 qr[8];
#pragma unroll
    for (int d4 = 0; d4 < 8; d4++) qr[d4] = *(const float4*)&qs[i * 36 + d4 * 4];
    int iy = i / 7, ix = i - iy * 7;
    int hri = wi * 7 + iy, wri = wj * 7 + ix;
    int ai = hri < 105 ? 0 : (hri < 109 ? 1 : 2);
    int bi = wri < 105 ? 0 : (wri < 109 ? 1 : 2);
    for (int jj = 0; jj < jn; jj++) {
      int j = j0 + jj;
      float s = 0.f;
#pragma unroll
      for (int d4 = 0; d4 < 8; d4++) {
        float4 kr = *(const float4*)&ksh[j * 36 + d4 * 4];
        s += qr[d4].x * kr.x + qr[d4].y * kr.y + qr[d4].z * kr.z + qr[d4].w * kr.w;
      }
      s *= 0.17677669529663687f;
      int jy = j / 7, jx = j - jy * 7;
      int rel = (iy - jy + 6) * 13 + (ix - jx + 6);
      s += bias_s[rel];
      if (shift) {
        int hrj = wi * 7 + jy, wrj = wj * 7 + jx;
        int aj = hrj < 105 ? 0 : (hrj < 109 ? 1 : 2);
        int bj2 = wrj < 105 ? 0 : (wrj < 109 ? 1 : 2);
        if (ai != aj || bi != bj2) s -= 100.f;
      }
      pb[i * 49 + j] = s;
    }
  }
  __syncthreads();

  if (tid < 49) {
    float m = -1e30f;
    for (int j = 0; j < 49; j++) m = fmaxf(m, pb[tid * 49 + j]);
    float sum = 0.f;
    for (int j = 0; j < 49; j++) {
      float e = __expf(pb[tid * 49 + j] - m);
      pb[tid * 49 + j] = e;
      sum += e;
    }
    float inv = 1.f / sum;
    for (int j = 0; j < 49; j++) pb[tid * 49 + j] *= inv;
  }
  __syncthreads();

  // out = P @ V -> q-slot cols (bf16), vectorized
  for (int o = tid; o < 392; o += 128) {
    int i = o >> 3, d4 = o & 7;
    float4 a = make_float4(0.f, 0.f, 0.f, 0.f);
    for (int j = 0; j < 49; j++) {
      float p = pb[i * 49 + j];
      float4 v = *(const float4*)&vsh[j * 36 + d4 * 4];
      a.x += p * v.x; a.y += p * v.y; a.z += p * v.z; a.w += p * v.w;
    }
    ushort4 uo = make_ushort4(f2bf(a.x), f2bf(a.y), f2bf(a.z), f2bf(a.w));
    *(ushort4*)&qkvbuf[base + (long)i * 480 + h * 32 + d4 * 4] = uo;
  }
}

// ---------------------------------------------------------------------------
// Kernel B3: proj via bf16 MFMA + residual scatter-add. 64 tokens/block.
// projf N-cols packed in permuted x3-channel order; projb indexed via orig_ch.
// ---------------------------------------------------------------------------
__global__ __launch_bounds__(256) void proj_mfma(const unsigned short* __restrict__ qkvbuf,
                                                 const unsigned short* __restrict__ projf,
                                                 const float* __restrict__ projb,
                                                 float* __restrict__ x3,
                                                 int shift) {
  __shared__ unsigned short ao[64 * 168];
  __shared__ int spos[64];
  int tid = threadIdx.x;
  int p0 = blockIdx.x * 64;
  if (tid < 64) spos[tid] = token_pos(p0 + tid, shift);
  for (int idx = tid; idx < 10240; idx += 256) {
    int t = idx / 160, ch = idx - t * 160;
    ao[t * 168 + ch] = qkvbuf[(long)(p0 + t) * 480 + ch];
  }
  __syncthreads();

  int w = tid >> 6, lane = tid & 63, quad = lane >> 4, l16 = lane & 15;
  floatx4 acc[10];
#pragma unroll
  for (int n = 0; n < 10; n++) acc[n] = (floatx4){0.f, 0.f, 0.f, 0.f};
  for (int ks = 0; ks < 5; ks++) {
    short8 a = *(const short8*)&ao[(w * 16 + l16) * 168 + ks * 32 + quad * 8];
    const short8* bp = (const short8*)projf + (ks * 10) * 64 + lane;
#pragma unroll
    for (int n = 0; n < 10; n++)
      acc[n] = __builtin_amdgcn_mfma_f32_16x16x32_bf16(a, bp[n * 64], acc[n], 0, 0, 0);
  }
#pragma unroll
  for (int n = 0; n < 10; n++) {
    int col = n * 16 + l16;           // permuted x3 channel
    float bv = projb[orig_ch(col)];
#pragma unroll
    for (int r = 0; r < 4; r++) {
      int tl = w * 16 + quad * 4 + r;
      long a = (long)spos[tl] * DIM + col;
      x3[a] = x3[a] + acc[n][r] + bv;
    }
  }
}

// ---------------------------------------------------------------------------
// Kernel C: LN2 + MLP via bf16 MFMA. 32 tokens/block, 4 waves.
// w1f rows / w2f cols packed with x3-channel permutation.
// ---------------------------------------------------------------------------
__global__ __launch_bounds__(256) void mlp_mfma(float* __restrict__ x3,
                                                const float* __restrict__ g,
                                                const float* __restrict__ bb,
                                                const unsigned short* __restrict__ w1f,
                                                const float* __restrict__ b1,
                                                const unsigned short* __restrict__ w2f,
                                                const float* __restrict__ b2) {
  __shared__ unsigned short lnv[32 * 168];   // bf16, row stride 168
  __shared__ unsigned short h1s[32 * 648];   // bf16, row stride 648

  int tid = threadIdx.x;
  long p0 = (long)blockIdx.x * 32;

  // ---- LN2: 8 threads per token ----
  {
    int t = tid >> 3, sub = tid & 7;
    const float* row = x3 + (p0 + t) * 160 + sub * 20;
    float xv[20];
    float s1 = 0.f, s2 = 0.f;
#pragma unroll
    for (int m = 0; m < 20; m++) { float v = row[m]; xv[m] = v; s1 += v; s2 += v * v; }
#pragma unroll
    for (int m = 1; m < 8; m <<= 1) { s1 += __shfl_xor(s1, m); s2 += __shfl_xor(s2, m); }
    float mu = s1 * (1.f / 160.f);
    float rs = rsqrtf(s2 * (1.f / 160.f) - mu * mu + 1e-5f);
#pragma unroll
    for (int m = 0; m < 20; m++) {
      int c = sub * 20 + m;
      int oc = orig_ch(c);
      lnv[t * 168 + c] = f2bf((xv[m] - mu) * rs * g[oc] + bb[oc]);
    }
  }
  __syncthreads();

  int w = tid >> 6, lane = tid & 63, quad = lane >> 4, l16 = lane & 15;

  // ---- fc1: wave w -> cols [w*160, w*160+160) ----
  floatx4 acc[2][10];
#pragma unroll
  for (int mf = 0; mf < 2; mf++)
#pragma unroll
    for (int n = 0; n < 10; n++) acc[mf][n] = (floatx4){0.f, 0.f, 0.f, 0.f};

  for (int ks = 0; ks < 5; ks++) {
    short8 a0 = *(const short8*)&lnv[l16 * 168 + ks * 32 + quad * 8];
    short8 a1 = *(const short8*)&lnv[(16 + l16) * 168 + ks * 32 + quad * 8];
    const short8* bp = (const short8*)w1f + (ks * 40 + w * 10) * 64 + lane;
#pragma unroll
    for (int n = 0; n < 10; n++) {
      short8 bf = bp[n * 64];
      acc[0][n] = __builtin_amdgcn_mfma_f32_16x16x32_bf16(a0, bf, acc[0][n], 0, 0, 0);
      acc[1][n] = __builtin_amdgcn_mfma_f32_16x16x32_bf16(a1, bf, acc[1][n], 0, 0, 0);
    }
  }

  // fc1 epilogue: bias + gelu -> h1s (bf16)
#pragma unroll
  for (int mf = 0; mf < 2; mf++)
#pragma unroll
    for (int n = 0; n < 10; n++) {
      int col = w * 160 + n * 16 + l16;
      float bv = b1[col];
#pragma unroll
      for (int r = 0; r < 4; r++) {
        int tok = mf * 16 + quad * 4 + r;
        h1s[tok * 648 + col] = f2bf(gelu_f(acc[mf][n][r] + bv));
      }
    }
  __syncthreads();

  // ---- fc2: wave w -> M-frag (w&1), N-frags [(w>>1)*5 .. +5), full K ----
  int mf = w & 1, nb = (w >> 1) * 5;
  floatx4 acc2[5];
#pragma unroll
  for (int n = 0; n < 5; n++) acc2[n] = (floatx4){0.f, 0.f, 0.f, 0.f};
  for (int ks = 0; ks < 20; ks++) {
    short8 a = *(const short8*)&h1s[(mf * 16 + l16) * 648 + ks * 32 + quad * 8];
    const short8* bp = (const short8*)w2f + (ks * 10 + nb) * 64 + lane;
#pragma unroll
    for (int n = 0; n < 5; n++)
      acc2[n] = __builtin_amdgcn_mfma_f32_16x16x32_bf16(a, bp[n * 64], acc2[n], 0, 0, 0);
  }

  // residual + bias writeout
#pragma unroll
  for (int n = 0; n < 5; n++) {
    int col = (nb + n) * 16 + l16;    // permuted x3 channel
    float bv = b2[orig_ch(col)];
#pragma unroll
    for (int r = 0; r < 4; r++) {
      int tok = mf * 16 + quad * 4 + r;
      long a = (p0 + tok) * 160 + col;
      x3[a] = x3[a] + acc2[n][r] + bv;
    }
  }
}

// ---------------------------------------------------------------------------
// Kernel D: y_planes[j][pos] = (x3 @ linw + linb)[pos][j], plane-major.
// linw rows indexed via orig_ch (x3 is permuted).
// ---------------------------------------------------------------------------
__global__ __launch_bounds__(256) void lin_kernel(const float* __restrict__ x3,
                                                  const float* __restrict__ linw,
                                                  const float* __restrict__ linb,
                                                  float* __restrict__ yp) {
  __shared__ float xs[16 * 160];
  __shared__ float ys[144 * 17];
  int tid = threadIdx.x;
  long p0 = (long)blockIdx.x * 16;
  for (int idx = tid; idx < 2560; idx += 256) xs[idx] = x3[p0 * DIM + idx];
  __syncthreads();
  if (tid < 144) {
    int j = tid;
    float acc[16];
    float bj = linb[j];
#pragma unroll
    for (int t2 = 0; t2 < 16; t2++) acc[t2] = bj;
    for (int i = 0; i < 160; i++) {
      float wv = linw[orig_ch(i) * 144 + j];
#pragma unroll
      for (int t2 = 0; t2 < 16; t2++) acc[t2] += xs[t2 * 160 + i] * wv;
    }
#pragma unroll
    for (int t2 = 0; t2 < 16; t2++) ys[j * 17 + t2] = acc[t2];
  }
  __syncthreads();
#pragma unroll
  for (int rep = 0; rep < 9; rep++) {
    int idx = tid + rep * 256;  // < 2304
    int j = idx >> 4, t2 = idx & 15;
    yp[(long)j * NPOS + p0 + t2] = ys[j * 17 + t2];
  }
}

// ---------------------------------------------------------------------------
// Kernel E: synthesis conv on plane-major y -> plane-major yt [16][NPOS]
// ---------------------------------------------------------------------------
__global__ __launch_bounds__(256) void syn_kernel(const float* __restrict__ yp,
                                                  const float* __restrict__ fsyn,
                                                  float* __restrict__ yt) {
  __shared__ float tileS[9 * 576];
  __shared__ float fsl[729];
  int tid = threadIdx.x;
  int blk = blockIdx.x;
  int b = blk / 784;
  int rem = blk - b * 784;
  int c = rem / 49;
  int tile = rem - c * 49;
  int y0 = (tile / 7) * 16, x0 = (tile % 7) * 16;

  for (int i = tid; i < 729; i += 256) fsl[i] = fsyn[i];
  for (int idx = tid; idx < 5184; idx += 256) {
    int k = idx / 576, r = idx - k * 576;
    int ly = r / 24, lx = r - ly * 24;
    int gy = y0 + ly - 4, gx = x0 + lx - 4;
    float v = 0.f;
    if (gy >= 0 && gy < HH && gx >= 0 && gx < WW)
      v = yp[(long)(k * 16 + c) * NPOS + (b * HH + gy) * WW + gx];
    tileS[idx] = v;
  }
  __syncthreads();

  int ty = tid >> 4, tx = tid & 15;
  float acc = 0.f;
  for (int k = 0; k < 9; k++) {
    const float* ts = &tileS[k * 576];
    const float* fk = &fsl[k * 81];
    for (int ky = 0; ky < 9; ky++)
#pragma unroll
      for (int kx = 0; kx < 9; kx++)
        acc += ts[(ty + ky) * 24 + (tx + kx)] * fk[ky * 9 + kx];
  }
  yt[(long)c * NPOS + (b * HH + (y0 + ty)) * WW + (x0 + tx)] = acc;
}

// ---------------------------------------------------------------------------
// Kernel F: final 1x1 conv from plane-major inputs -> out [B,16,H,W]
// ---------------------------------------------------------------------------
__global__ __launch_bounds__(256) void final_kernel(const float* __restrict__ yt,
                                                    const float* __restrict__ yp,
                                                    const float* __restrict__ convw,
                                                    const float* __restrict__ convb,
                                                    float* __restrict__ out) {
  long pos = (long)blockIdx.x * 256 + threadIdx.x;
  if (pos >= NPOS) return;
  int b = (int)(pos / (HH * WW));
  int hw = (int)(pos - (long)b * HH * WW);

  float acc[16];
#pragma unroll
  for (int co = 0; co < 16; co++) acc[co] = convb[co];
  for (int c = 0; c < 16; c++) {
    float v = yt[(long)c * NPOS + pos];
#pragma unroll
    for (int co = 0; co < 16; co++) acc[co] += v * convw[co * 160 + c];
  }
  for (int j = 0; j < 144; j++) {
    float v = yp[(long)j * NPOS + pos];
#pragma unroll
    for (int co = 0; co < 16; co++) acc[co] += v * convw[co * 160 + 16 + j];
  }
#pragma unroll
  for (int co = 0; co < 16; co++)
    out[(((long)b * 16 + co) * HH * WW) + hw] = acc[co];
}

// ---------------------------------------------------------------------------
extern "C" void kernel_launch(void* const* d_in, const int* in_sizes, int n_in,
                              void* d_out, int out_size, void* d_ws, size_t ws_size,
                              hipStream_t stream) {
  const float* x     = (const float*)d_in[0];
  const float* fana  = (const float*)d_in[1];
  const float* fsyn  = (const float*)d_in[2];
  const float* ln1g  = (const float*)d_in[3];
  const float* ln1b  = (const float*)d_in[4];
  const float* qkvw  = (const float*)d_in[5];
  const float* qkvb  = (const float*)d_in[6];
  const float* projw = (const float*)d_in[7];
  const float* projb = (const float*)d_in[8];
  const float* rpb   = (const float*)d_in[9];
  const float* ln2g  = (const float*)d_in[10];
  const float* ln2b  = (const float*)d_in[11];
  const float* w1    = (const float*)d_in[12];
  const float* b1    = (const float*)d_in[13];
  const float* w2    = (const float*)d_in[14];
  const float* b2    = (const float*)d_in[15];
  const float* linw  = (const float*)d_in[16];
  const float* linb  = (const float*)d_in[17];
  const float* convw = (const float*)d_in[18];
  const float* convb = (const float*)d_in[19];
  float* out = (float*)d_out;

  char* ws = (char*)d_ws;
  float* x3 = (float*)ws;                           // 64,225,280 B, live whole run
  char* region2 = ws + 64225280;                    // time-shared:
  unsigned short* qkvbuf = (unsigned short*)region2;           // bf16 [NPOS x 480]
  unsigned short* packs  = (unsigned short*)(region2 + 96337920);
  unsigned short* qkvf = packs;                     // 76800 ush
  unsigned short* projf = packs + 76800;            // 25600 ush
  unsigned short* w1f   = packs + 102400;           // 102400 ush
  unsigned short* w2f   = packs + 204800;           // 102400 ush
  float* yp = (float*)region2;                      // lin/syn/final phase
  float* yt = (float*)ws;                           // aliases x3 (dead after lin)

  ana_kernel<<<BB * 49, 256, 0, stream>>>(x, fana, x3);
  for (int i = 0; i < 2; i++) {
    int shift = i ? (WIN / 2) : 0;
    pack_kernel<<<300, 256, 0, stream>>>(qkvw + i * 76800, qkvf, 30, 480, 76800, 1, 0);
    pack_kernel<<<100, 256, 0, stream>>>(projw + i * 25600, projf, 10, 160, 25600, 0, 1);
    pack_kernel<<<400, 256, 0, stream>>>(w1 + i * 102400, w1f, 40, 640, 102400, 1, 0);
    pack_kernel<<<400, 256, 0, stream>>>(w2 + i * 102400, w2f, 10, 160, 102400, 0, 1);
    qkv_mfma<<<NPOS / 64, 256, 0, stream>>>(x3, ln1g + i * 160, ln1b + i * 160,
                                            qkvf, qkvb + i * 480, qkvbuf, shift);
    attn_core<<<BB * NWIN * HEADS, 128, 0, stream>>>(qkvbuf, rpb + i * 169 * 5, shift);
    proj_mfma<<<NPOS / 64, 256, 0, stream>>>(qkvbuf, projf, projb + i * 160, x3, shift);
    mlp_mfma<<<NPOS / 32, 256, 0, stream>>>(x3, ln2g + i * 160, ln2b + i * 160,
                                            w1f, b1 + i * 640, w2f, b2 + i * 160);
  }
  lin_kernel<<<NPOS / 16, 256, 0, stream>>>(x3, linw, linb, yp);
  syn_kernel<<<BB * 16 * 49, 256, 0, stream>>>(yp, fsyn, yt);
  final_kernel<<<(NPOS + 255) / 256, 256, 0, stream>>>(yt, yp, convw, convb, out);
}

// Round 6
// 1426.985 us; speedup vs baseline: 28.1651x; 1.0877x over previous
//
#include <hip/hip_runtime.h>
#include <hip/hip_bf16.h>
#include <math.h>

#define BB 8
#define CC 16
#define HH 112
#define WW 112
#define KK 9
#define FS 9
#define WIN 7
#define DIM 160
#define HEADS 5
#define HDIM 32
#define MLPD 640
#define NWIN 256          // (112/7)^2
#define NPOS (BB*HH*WW)   // 100352

typedef __attribute__((ext_vector_type(8))) short short8;
typedef __attribute__((ext_vector_type(4))) float floatx4;

__device__ __forceinline__ unsigned short f2bf(float f) {
  union { float f; unsigned u; } v; v.f = f;
  unsigned r = v.u + 0x7fffu + ((v.u >> 16) & 1u);
  return (unsigned short)(r >> 16);
}
__device__ __forceinline__ float bf2f(unsigned short u) {
  union { unsigned u; float f; } v; v.u = ((unsigned)u) << 16;
  return v.f;
}
// gelu tanh-approx, exp-based (same formula as jax.nn.gelu, no libm tanh)
__device__ __forceinline__ float gelu_f(float a) {
  float z = 0.7978845608028654f * (a + 0.044715f * a * a * a);
  return a * __builtin_amdgcn_rcpf(1.f + __expf(-2.f * z));
}
// x3 uses internal channel order ch' = c*10 + k (k=0..8 subbands, 9 = relu skip).
// orig_ch maps internal -> reference channel (k*16+c for k<9, 144+c for k=9).
__device__ __forceinline__ int orig_ch(int ch) {
  int c = ch / 10, k = ch - c * 10;
  return (k < 9) ? k * 16 + c : 144 + c;
}

// ---------------------------------------------------------------------------
// Kernel A: relu + analysis filter bank -> x3 [B,H,W,160] (permuted channels)
// ---------------------------------------------------------------------------
__global__ __launch_bounds__(256) void ana_kernel(const float* __restrict__ x,
                                                  const float* __restrict__ fana,
                                                  float* __restrict__ x3) {
  __shared__ float tileS[16 * 576];  // 16 ch x 24x24
  __shared__ float fs[729];
  int tid = threadIdx.x;
  int blk = blockIdx.x;
  int b = blk / 49;
  int tile = blk - b * 49;
  int y0 = (tile / 7) * 16, x0 = (tile % 7) * 16;

  for (int i = tid; i < 729; i += 256) fs[i] = fana[i];
  for (int idx = tid; idx < 9216; idx += 256) {
    int c = idx / 576, r = idx - c * 576;
    int ly = r / 24, lx = r - ly * 24;
    int gy = y0 + ly - 4, gx = x0 + lx - 4;
    float v = 0.f;
    if (gy >= 0 && gy < HH && gx >= 0 && gx < WW)
      v = fmaxf(x[(((long)b * CC + c) * HH + gy) * WW + gx], 0.f);
    tileS[idx] = v;
  }
  __syncthreads();

  int ty = tid >> 4, tx = tid & 15;
  long obase = (((long)b * HH + (y0 + ty)) * WW + (x0 + tx)) * DIM;
  for (int c = 0; c < 16; c++) {
    float acc[9];
#pragma unroll
    for (int k = 0; k < 9; k++) acc[k] = 0.f;
    const float* ts = &tileS[c * 576];
    for (int ky = 0; ky < 9; ky++)
      for (int kx = 0; kx < 9; kx++) {
        float v = ts[(ty + ky) * 24 + (tx + kx)];
#pragma unroll
        for (int k = 0; k < 9; k++) acc[k] += v * fs[k * 81 + ky * 9 + kx];
      }
    float skip = ts[(ty + 4) * 24 + (tx + 4)];
    float2* dst = (float2*)&x3[obase + c * 10];
    dst[0] = make_float2(acc[0], acc[1]);
    dst[1] = make_float2(acc[2], acc[3]);
    dst[2] = make_float2(acc[4], acc[5]);
    dst[3] = make_float2(acc[6], acc[7]);
    dst[4] = make_float2(acc[8], skip);
  }
}

// ---------------------------------------------------------------------------
// token_pos: window-ordered flat token p -> source position in [B,H,W]
// ---------------------------------------------------------------------------
__device__ __forceinline__ int token_pos(int p, int shift) {
  int w = p / 49;
  int t = p - w * 49;
  int b = w >> 8;
  int wid = w & 255;
  int wi = wid >> 4, wj = wid & 15;
  int iy = t / 7, ix = t - (t / 7) * 7;
  int hy = (wi * 7 + iy + shift) % HH;
  int wx = (wj * 7 + ix + shift) % WW;
  return (b * HH + hy) * WW + wx;
}

// ---------------------------------------------------------------------------
// pack4_kernel: all four weight matrices -> bf16 MFMA B-fragment layout in one
// launch. Ranges: [0,300) qkv, [300,400) proj, [400,800) w1, [800,1200) w2.
// ---------------------------------------------------------------------------
__device__ __forceinline__ void pack_one(const float* __restrict__ src,
                                         unsigned short* __restrict__ dst,
                                         int nfcnt, int ncols, int nelems,
                                         int permK, int permN, int idx) {
  if (idx >= nelems) return;
  int j = idx & 7;
  int lane = (idx >> 3) & 63;
  int t = idx >> 9;
  int nf = t % nfcnt, ks = t / nfcnt;
  int k = ks * 32 + (lane >> 4) * 8 + j;
  int n = nf * 16 + (lane & 15);
  if (permK) k = orig_ch(k);
  if (permN) n = orig_ch(n);
  dst[idx] = f2bf(src[k * ncols + n]);
}

__global__ __launch_bounds__(256) void pack4_kernel(const float* __restrict__ qkvw,
                                                    const float* __restrict__ projw,
                                                    const float* __restrict__ w1,
                                                    const float* __restrict__ w2,
                                                    unsigned short* __restrict__ qkvf,
                                                    unsigned short* __restrict__ projf,
                                                    unsigned short* __restrict__ w1f,
                                                    unsigned short* __restrict__ w2f) {
  int blk = blockIdx.x, tid = threadIdx.x;
  if (blk < 300)      pack_one(qkvw,  qkvf,  30, 480, 76800,  1, 0, blk * 256 + tid);
  else if (blk < 400) pack_one(projw, projf, 10, 160, 25600,  0, 1, (blk - 300) * 256 + tid);
  else if (blk < 800) pack_one(w1,    w1f,   40, 640, 102400, 1, 0, (blk - 400) * 256 + tid);
  else                pack_one(w2,    w2f,   10, 160, 102400, 0, 1, (blk - 800) * 256 + tid);
}

// ---------------------------------------------------------------------------
// Kernel B1: LN1 + qkv GEMM via bf16 MFMA. 64 tokens/block (window-ordered).
// ---------------------------------------------------------------------------
__global__ __launch_bounds__(256) void qkv_mfma(const float* __restrict__ x3,
                                                const float* __restrict__ g,
                                                const float* __restrict__ bb,
                                                const unsigned short* __restrict__ qkvf,
                                                const float* __restrict__ qkvb,
                                                unsigned short* __restrict__ qkvbuf,
                                                int shift) {
  __shared__ unsigned short lnv[64 * 168];  // bf16, row stride 168

  int tid = threadIdx.x;
  int p0 = blockIdx.x * 64;

  // ---- LN1: 4 threads per token, 40 elems each (permuted channel space) ----
  {
    int t = tid >> 2, sub = tid & 3;
    int pos = token_pos(p0 + t, shift);
    const float* row = x3 + (long)pos * 160 + sub * 40;
    float xv[40];
    float s1 = 0.f, s2 = 0.f;
#pragma unroll
    for (int m = 0; m < 40; m++) { float v = row[m]; xv[m] = v; s1 += v; s2 += v * v; }
    s1 += __shfl_xor(s1, 1); s2 += __shfl_xor(s2, 1);
    s1 += __shfl_xor(s1, 2); s2 += __shfl_xor(s2, 2);
    float mu = s1 * (1.f / 160.f);
    float rs = rsqrtf(s2 * (1.f / 160.f) - mu * mu + 1e-5f);
#pragma unroll
    for (int m = 0; m < 40; m++) {
      int c = sub * 40 + m;
      int oc = orig_ch(c);
      lnv[t * 168 + c] = f2bf((xv[m] - mu) * rs * g[oc] + bb[oc]);
    }
  }
  __syncthreads();

  int w = tid >> 6, lane = tid & 63, quad = lane >> 4, l16 = lane & 15;

#pragma unroll
  for (int half = 0; half < 2; half++) {
    floatx4 acc[15];
#pragma unroll
    for (int n = 0; n < 15; n++) acc[n] = (floatx4){0.f, 0.f, 0.f, 0.f};
    for (int ks = 0; ks < 5; ks++) {
      short8 a = *(const short8*)&lnv[(w * 16 + l16) * 168 + ks * 32 + quad * 8];
      const short8* bp = (const short8*)qkvf + (ks * 30 + half * 15) * 64 + lane;
#pragma unroll
      for (int n = 0; n < 15; n++)
        acc[n] = __builtin_amdgcn_mfma_f32_16x16x32_bf16(a, bp[n * 64], acc[n], 0, 0, 0);
    }
#pragma unroll
    for (int n = 0; n < 15; n++) {
      int col = (half * 15 + n) * 16 + l16;
      float bv = qkvb[col];
#pragma unroll
      for (int r = 0; r < 4; r++) {
        int tok = p0 + w * 16 + quad * 4 + r;
        qkvbuf[(long)tok * 480 + col] = f2bf(acc[n][r] + bv);
      }
    }
  }
}

// ---------------------------------------------------------------------------
// Kernel B2: attention core, one block per (window, head), 128 threads.
// ---------------------------------------------------------------------------
__global__ __launch_bounds__(128) void attn_core(unsigned short* __restrict__ qkvbuf,
                                                 const float* __restrict__ rpb,
                                                 int shift) {
  __shared__ float qs[49 * 36], ksh[49 * 36], vsh[49 * 36];  // 16B-aligned rows
  __shared__ float pb[49 * 49];
  __shared__ float bias_s[169];

  int tid = threadIdx.x;
  int bid = blockIdx.x;
  int w = bid / 5, h = bid - (bid / 5) * 5;
  int wid = w & 255;
  int wi = wid >> 4, wj = wid & 15;
  long base = (long)w * 49 * 480;

  for (int i = tid; i < 169; i += 128) bias_s[i] = rpb[i * 5 + h];

  // load q,k,v [49,32] for this head, vectorized ushort4 -> float4
  for (int idx = tid; idx < 1176; idx += 128) {
    int m = idx / 392, r = idx - m * 392;
    int t = r >> 3, d4 = r & 7;
    ushort4 u = *(const ushort4*)&qkvbuf[base + (long)t * 480 + m * 160 + h * 32 + d4 * 4];
    float4 f = make_float4(bf2f(u.x), bf2f(u.y), bf2f(u.z), bf2f(u.w));
    float* dst = (m == 0) ? qs : (m == 1) ? ksh : vsh;
    *(float4*)&dst[t * 36 + d4 * 4] = f;
  }
  __syncthreads();

  // scores: thread (row i, half) with q-row cached in registers
  if (tid < 98) {
    int i = tid >> 1, halfj = tid & 1;
    int j0 = halfj * 25, jn = halfj ? 24 : 25;
    float4 qr[8];
#pragma unroll
    for (int d4 = 0; d4 < 8; d4++) qr[d4] = *(const float4*)&qs[i * 36 + d4 * 4];
    int iy = i / 7, ix = i - iy * 7;
    int hri = wi * 7 + iy, wri = wj * 7 + ix;
    int ai = hri < 105 ? 0 : (hri < 109 ? 1 : 2);
    int bi = wri < 105 ? 0 : (wri < 109 ? 1 : 2);
    for (int jj = 0; jj < jn; jj++) {
      int j = j0 + jj;
      float s = 0.f;
#pragma unroll
      for (int d4 = 0; d4 < 8; d4++) {
        float4 kr = *(const float4*)&ksh[j * 36 + d4 * 4];
        s += qr[d4].x * kr.x + qr[d4].y * kr.y + qr[d4].z * kr.z + qr[d4].w * kr.w;
      }
      s *= 0.17677669529663687f;
      int jy = j / 7, jx = j - jy * 7;
      int rel = (iy - jy + 6) * 13 + (ix - jx + 6);
      s += bias_s[rel];
      if (shift) {
        int hrj = wi * 7 + jy, wrj = wj * 7 + jx;
        int aj = hrj < 105 ? 0 : (hrj < 109 ? 1 : 2);
        int bj2 = wrj < 105 ? 0 : (wrj < 109 ? 1 : 2);
        if (ai != aj || bi != bj2) s -= 100.f;
      }
      pb[i * 49 + j] = s;
    }
  }
  __syncthreads();

  if (tid < 49) {
    float m = -1e30f;
    for (int j = 0; j < 49; j++) m = fmaxf(m, pb[tid * 49 + j]);
    float sum = 0.f;
    for (int j = 0; j < 49; j++) {
      float e = __expf(pb[tid * 49 + j] - m);
      pb[tid * 49 + j] = e;
      sum += e;
    }
    float inv = 1.f / sum;
    for (int j = 0; j < 49; j++) pb[tid * 49 + j] *= inv;
  }
  __syncthreads();

  // out = P @ V -> q-slot cols (bf16), vectorized
  for (int o = tid; o < 392; o += 128) {
    int i = o >> 3, d4 = o & 7;
    float4 a = make_float4(0.f, 0.f, 0.f, 0.f);
    for (int j = 0; j < 49; j++) {
      float p = pb[i * 49 + j];
      float4 v = *(const float4*)&vsh[j * 36 + d4 * 4];
      a.x += p * v.x; a.y += p * v.y; a.z += p * v.z; a.w += p * v.w;
    }
    ushort4 uo = make_ushort4(f2bf(a.x), f2bf(a.y), f2bf(a.z), f2bf(a.w));
    *(ushort4*)&qkvbuf[base + (long)i * 480 + h * 32 + d4 * 4] = uo;
  }
}

// ---------------------------------------------------------------------------
// Kernel B3: proj via bf16 MFMA + residual scatter-add. 64 tokens/block.
// ---------------------------------------------------------------------------
__global__ __launch_bounds__(256) void proj_mfma(const unsigned short* __restrict__ qkvbuf,
                                                 const unsigned short* __restrict__ projf,
                                                 const float* __restrict__ projb,
                                                 float* __restrict__ x3,
                                                 int shift) {
  __shared__ unsigned short ao[64 * 168];
  __shared__ int spos[64];
  int tid = threadIdx.x;
  int p0 = blockIdx.x * 64;
  if (tid < 64) spos[tid] = token_pos(p0 + tid, shift);
  for (int idx = tid; idx < 10240; idx += 256) {
    int t = idx / 160, ch = idx - t * 160;
    ao[t * 168 + ch] = qkvbuf[(long)(p0 + t) * 480 + ch];
  }
  __syncthreads();

  int w = tid >> 6, lane = tid & 63, quad = lane >> 4, l16 = lane & 15;
  floatx4 acc[10];
#pragma unroll
  for (int n = 0; n < 10; n++) acc[n] = (floatx4){0.f, 0.f, 0.f, 0.f};
  for (int ks = 0; ks < 5; ks++) {
    short8 a = *(const short8*)&ao[(w * 16 + l16) * 168 + ks * 32 + quad * 8];
    const short8* bp = (const short8*)projf + (ks * 10) * 64 + lane;
#pragma unroll
    for (int n = 0; n < 10; n++)
      acc[n] = __builtin_amdgcn_mfma_f32_16x16x32_bf16(a, bp[n * 64], acc[n], 0, 0, 0);
  }
#pragma unroll
  for (int n = 0; n < 10; n++) {
    int col = n * 16 + l16;           // permuted x3 channel
    float bv = projb[orig_ch(col)];
#pragma unroll
    for (int r = 0; r < 4; r++) {
      int tl = w * 16 + quad * 4 + r;
      long a = (long)spos[tl] * DIM + col;
      x3[a] = x3[a] + acc[n][r] + bv;
    }
  }
}

// ---------------------------------------------------------------------------
// Kernel C: LN2 + MLP via bf16 MFMA. 32 tokens/block, 4 waves.
// ---------------------------------------------------------------------------
__global__ __launch_bounds__(256) void mlp_mfma(float* __restrict__ x3,
                                                const float* __restrict__ g,
                                                const float* __restrict__ bb,
                                                const unsigned short* __restrict__ w1f,
                                                const float* __restrict__ b1,
                                                const unsigned short* __restrict__ w2f,
                                                const float* __restrict__ b2) {
  __shared__ unsigned short lnv[32 * 168];   // bf16, row stride 168
  __shared__ unsigned short h1s[32 * 648];   // bf16, row stride 648

  int tid = threadIdx.x;
  long p0 = (long)blockIdx.x * 32;

  // ---- LN2: 8 threads per token ----
  {
    int t = tid >> 3, sub = tid & 7;
    const float* row = x3 + (p0 + t) * 160 + sub * 20;
    float xv[20];
    float s1 = 0.f, s2 = 0.f;
#pragma unroll
    for (int m = 0; m < 20; m++) { float v = row[m]; xv[m] = v; s1 += v; s2 += v * v; }
#pragma unroll
    for (int m = 1; m < 8; m <<= 1) { s1 += __shfl_xor(s1, m); s2 += __shfl_xor(s2, m); }
    float mu = s1 * (1.f / 160.f);
    float rs = rsqrtf(s2 * (1.f / 160.f) - mu * mu + 1e-5f);
#pragma unroll
    for (int m = 0; m < 20; m++) {
      int c = sub * 20 + m;
      int oc = orig_ch(c);
      lnv[t * 168 + c] = f2bf((xv[m] - mu) * rs * g[oc] + bb[oc]);
    }
  }
  __syncthreads();

  int w = tid >> 6, lane = tid & 63, quad = lane >> 4, l16 = lane & 15;

  // ---- fc1: wave w -> cols [w*160, w*160+160) ----
  floatx4 acc[2][10];
#pragma unroll
  for (int mf = 0; mf < 2; mf++)
#pragma unroll
    for (int n = 0; n < 10; n++) acc[mf][n] = (floatx4){0.f, 0.f, 0.f, 0.f};

  for (int ks = 0; ks < 5; ks++) {
    short8 a0 = *(const short8*)&lnv[l16 * 168 + ks * 32 + quad * 8];
    short8 a1 = *(const short8*)&lnv[(16 + l16) * 168 + ks * 32 + quad * 8];
    const short8* bp = (const short8*)w1f + (ks * 40 + w * 10) * 64 + lane;
#pragma unroll
    for (int n = 0; n < 10; n++) {
      short8 bf = bp[n * 64];
      acc[0][n] = __builtin_amdgcn_mfma_f32_16x16x32_bf16(a0, bf, acc[0][n], 0, 0, 0);
      acc[1][n] = __builtin_amdgcn_mfma_f32_16x16x32_bf16(a1, bf, acc[1][n], 0, 0, 0);
    }
  }

  // fc1 epilogue: bias + gelu -> h1s (bf16)
#pragma unroll
  for (int mf = 0; mf < 2; mf++)
#pragma unroll
    for (int n = 0; n < 10; n++) {
      int col = w * 160 + n * 16 + l16;
      float bv = b1[col];
#pragma unroll
      for (int r = 0; r < 4; r++) {
        int tok = mf * 16 + quad * 4 + r;
        h1s[tok * 648 + col] = f2bf(gelu_f(acc[mf][n][r] + bv));
      }
    }
  __syncthreads();

  // ---- fc2: wave w -> M-frag (w&1), N-frags [(w>>1)*5 .. +5), full K ----
  int mf = w & 1, nb = (w >> 1) * 5;
  floatx4 acc2[5];
#pragma unroll
  for (int n = 0; n < 5; n++) acc2[n] = (floatx4){0.f, 0.f, 0.f, 0.f};
  for (int ks = 0; ks < 20; ks++) {
    short8 a = *(const short8*)&h1s[(mf * 16 + l16) * 648 + ks * 32 + quad * 8];
    const short8* bp = (const short8*)w2f + (ks * 10 + nb) * 64 + lane;
#pragma unroll
    for (int n = 0; n < 5; n++)
      acc2[n] = __builtin_amdgcn_mfma_f32_16x16x32_bf16(a, bp[n * 64], acc2[n], 0, 0, 0);
  }

  // residual + bias writeout
#pragma unroll
  for (int n = 0; n < 5; n++) {
    int col = (nb + n) * 16 + l16;    // permuted x3 channel
    float bv = b2[orig_ch(col)];
#pragma unroll
    for (int r = 0; r < 4; r++) {
      int tok = mf * 16 + quad * 4 + r;
      long a = (p0 + tok) * 160 + col;
      x3[a] = x3[a] + acc2[n][r] + bv;
    }
  }
}

// ---------------------------------------------------------------------------
// Kernel D: y_planes[j][pos] = (x3 @ linw + linb)[pos][j], plane-major.
// ---------------------------------------------------------------------------
__global__ __launch_bounds__(256) void lin_kernel(const float* __restrict__ x3,
                                                  const float* __restrict__ linw,
                                                  const float* __restrict__ linb,
                                                  float* __restrict__ yp) {
  __shared__ float xs[16 * 160];
  __shared__ float ys[144 * 17];
  int tid = threadIdx.x;
  long p0 = (long)blockIdx.x * 16;
  for (int idx = tid; idx < 2560; idx += 256) xs[idx] = x3[p0 * DIM + idx];
  __syncthreads();
  if (tid < 144) {
    int j = tid;
    float acc[16];
    float bj = linb[j];
#pragma unroll
    for (int t2 = 0; t2 < 16; t2++) acc[t2] = bj;
    for (int i = 0; i < 160; i++) {
      float wv = linw[orig_ch(i) * 144 + j];
#pragma unroll
      for (int t2 = 0; t2 < 16; t2++) acc[t2] += xs[t2 * 160 + i] * wv;
    }
#pragma unroll
    for (int t2 = 0; t2 < 16; t2++) ys[j * 17 + t2] = acc[t2];
  }
  __syncthreads();
#pragma unroll
  for (int rep = 0; rep < 9; rep++) {
    int idx = tid + rep * 256;  // < 2304
    int j = idx >> 4, t2 = idx & 15;
    yp[(long)j * NPOS + p0 + t2] = ys[j * 17 + t2];
  }
}

// ---------------------------------------------------------------------------
// Kernel E: synthesis conv, sliding-window register blocking.
// Block = 256 thr = 16 rows x 16 col-groups; tile 16x112 (full width);
// thread computes 7 consecutive outputs; one plane staged at a time.
// ---------------------------------------------------------------------------
__global__ __launch_bounds__(256) void syn_kernel(const float* __restrict__ yp,
                                                  const float* __restrict__ fsyn,
                                                  float* __restrict__ yt) {
  __shared__ float tileS[24 * 120];  // one plane halo: 24 rows x 120 cols
  __shared__ float fsl[729];
  int tid = threadIdx.x;
  int blk = blockIdx.x;
  int tile = blk % 7;                 // row tile (16 rows)
  int c = (blk / 7) % 16;
  int b = blk / 112;
  int ty0 = tile * 16;

  for (int i = tid; i < 729; i += 256) fsl[i] = fsyn[i];

  int ty = tid >> 4, txg = tid & 15;  // output row 0..15, col-group 0..15
  float acc[7];
#pragma unroll
  for (int w = 0; w < 7; w++) acc[w] = 0.f;

  for (int k = 0; k < 9; k++) {
    const float* plane = yp + (long)(k * 16 + c) * NPOS + (long)b * HH * WW;
    __syncthreads();  // previous compute done before overwrite
    for (int idx = tid; idx < 2880; idx += 256) {
      int ly = idx / 120, lx = idx - ly * 120;
      int gy = ty0 + ly - 4, gx = lx - 4;
      float v = 0.f;
      if (gy >= 0 && gy < HH && gx >= 0 && gx < WW) v = plane[gy * WW + gx];
      tileS[idx] = v;
    }
    __syncthreads();

#pragma unroll
    for (int ky = 0; ky < 9; ky++) {
      const float* row = &tileS[(ty + ky) * 120 + txg * 7];
      float rr[15];
#pragma unroll
      for (int i = 0; i < 15; i++) rr[i] = row[i];
      const float* fk = &fsl[k * 81 + ky * 9];
#pragma unroll
      for (int kx = 0; kx < 9; kx++) {
        float f = fk[kx];
#pragma unroll
        for (int w = 0; w < 7; w++) acc[w] += rr[kx + w] * f;
      }
    }
  }

  long obase = (long)c * NPOS + ((long)b * HH + (ty0 + ty)) * WW + txg * 7;
#pragma unroll
  for (int w = 0; w < 7; w++) yt[obase + w] = acc[w];
}

// ---------------------------------------------------------------------------
// Kernel F: final 1x1 conv from plane-major inputs -> out [B,16,H,W]
// ---------------------------------------------------------------------------
__global__ __launch_bounds__(256) void final_kernel(const float* __restrict__ yt,
                                                    const float* __restrict__ yp,
                                                    const float* __restrict__ convw,
                                                    const float* __restrict__ convb,
                                                    float* __restrict__ out) {
  long pos = (long)blockIdx.x * 256 + threadIdx.x;
  if (pos >= NPOS) return;
  int b = (int)(pos / (HH * WW));
  int hw = (int)(pos - (long)b * HH * WW);

  float acc[16];
#pragma unroll
  for (int co = 0; co < 16; co++) acc[co] = convb[co];
  for (int c = 0; c < 16; c++) {
    float v = yt[(long)c * NPOS + pos];
#pragma unroll
    for (int co = 0; co < 16; co++) acc[co] += v * convw[co * 160 + c];
  }
  for (int j = 0; j < 144; j++) {
    float v = yp[(long)j * NPOS + pos];
#pragma unroll
    for (int co = 0; co < 16; co++) acc[co] += v * convw[co * 160 + 16 + j];
  }
#pragma unroll
  for (int co = 0; co < 16; co++)
    out[(((long)b * 16 + co) * HH * WW) + hw] = acc[co];
}

// ---------------------------------------------------------------------------
extern "C" void kernel_launch(void* const* d_in, const int* in_sizes, int n_in,
                              void* d_out, int out_size, void* d_ws, size_t ws_size,
                              hipStream_t stream) {
  const float* x     = (const float*)d_in[0];
  const float* fana  = (const float*)d_in[1];
  const float* fsyn  = (const float*)d_in[2];
  const float* ln1g  = (const float*)d_in[3];
  const float* ln1b  = (const float*)d_in[4];
  const float* qkvw  = (const float*)d_in[5];
  const float* qkvb  = (const float*)d_in[6];
  const float* projw = (const float*)d_in[7];
  const float* projb = (const float*)d_in[8];
  const float* rpb   = (const float*)d_in[9];
  const float* ln2g  = (const float*)d_in[10];
  const float* ln2b  = (const float*)d_in[11];
  const float* w1    = (const float*)d_in[12];
  const float* b1    = (const float*)d_in[13];
  const float* w2    = (const float*)d_in[14];
  const float* b2    = (const float*)d_in[15];
  const float* linw  = (const float*)d_in[16];
  const float* linb  = (const float*)d_in[17];
  const float* convw = (const float*)d_in[18];
  const float* convb = (const float*)d_in[19];
  float* out = (float*)d_out;

  char* ws = (char*)d_ws;
  float* x3 = (float*)ws;                           // 64,225,280 B, live whole run
  char* region2 = ws + 64225280;                    // time-shared:
  unsigned short* qkvbuf = (unsigned short*)region2;           // bf16 [NPOS x 480]
  unsigned short* packs  = (unsigned short*)(region2 + 96337920);
  unsigned short* qkvf = packs;                     // 76800 ush
  unsigned short* projf = packs + 76800;            // 25600 ush
  unsigned short* w1f   = packs + 102400;           // 102400 ush
  unsigned short* w2f   = packs + 204800;           // 102400 ush
  float* yp = (float*)region2;                      // lin/syn/final phase
  float* yt = (float*)ws;                           // aliases x3 (dead after lin)

  ana_kernel<<<BB * 49, 256, 0, stream>>>(x, fana, x3);
  for (int i = 0; i < 2; i++) {
    int shift = i ? (WIN / 2) : 0;
    pack4_kernel<<<1200, 256, 0, stream>>>(qkvw + i * 76800, projw + i * 25600,
                                           w1 + i * 102400, w2 + i * 102400,
                                           qkvf, projf, w1f, w2f);
    qkv_mfma<<<NPOS / 64, 256, 0, stream>>>(x3, ln1g + i * 160, ln1b + i * 160,
                                            qkvf, qkvb + i * 480, qkvbuf, shift);
    attn_core<<<BB * NWIN * HEADS, 128, 0, stream>>>(qkvbuf, rpb + i * 169 * 5, shift);
    proj_mfma<<<NPOS / 64, 256, 0, stream>>>(qkvbuf, projf, projb + i * 160, x3, shift);
    mlp_mfma<<<NPOS / 32, 256, 0, stream>>>(x3, ln2g + i * 160, ln2b + i * 160,
                                            w1f, b1 + i * 640, w2f, b2 + i * 160);
  }
  lin_kernel<<<NPOS / 16, 256, 0, stream>>>(x3, linw, linb, yp);
  syn_kernel<<<BB * 16 * 7, 256, 0, stream>>>(yp, fsyn, yt);
  final_kernel<<<(NPOS + 255) / 256, 256, 0, stream>>>(yt, yp, convw, convb, out);
}

// Round 7
// 1266.222 us; speedup vs baseline: 31.7410x; 1.1270x over previous
//
#include <hip/hip_runtime.h>
#include <hip/hip_bf16.h>
#include <math.h>

#define BB 8
#define CC 16
#define HH 112
#define WW 112
#define KK 9
#define FS 9
#define WIN 7
#define DIM 160
#define HEADS 5
#define HDIM 32
#define MLPD 640
#define NWIN 256          // (112/7)^2
#define NPOS (BB*HH*WW)   // 100352

typedef __attribute__((ext_vector_type(8))) short short8;
typedef __attribute__((ext_vector_type(4))) float floatx4;

__device__ __forceinline__ unsigned short f2bf(float f) {
  union { float f; unsigned u; } v; v.f = f;
  unsigned r = v.u + 0x7fffu + ((v.u >> 16) & 1u);
  return (unsigned short)(r >> 16);
}
__device__ __forceinline__ float bf2f(unsigned short u) {
  union { unsigned u; float f; } v; v.u = ((unsigned)u) << 16;
  return v.f;
}
// gelu tanh-approx, exp-based (same formula as jax.nn.gelu, no libm tanh)
__device__ __forceinline__ float gelu_f(float a) {
  float z = 0.7978845608028654f * (a + 0.044715f * a * a * a);
  return a * __builtin_amdgcn_rcpf(1.f + __expf(-2.f * z));
}
// x3 uses internal channel order ch' = c*10 + k (k=0..8 subbands, 9 = relu skip).
// orig_ch maps internal -> reference channel (k*16+c for k<9, 144+c for k=9).
__device__ __forceinline__ int orig_ch(int ch) {
  int c = ch / 10, k = ch - c * 10;
  return (k < 9) ? k * 16 + c : 144 + c;
}

// ---------------------------------------------------------------------------
// Kernel A: relu + analysis filter bank -> x3 [B,H,W,160] (permuted channels)
// ---------------------------------------------------------------------------
__global__ __launch_bounds__(256) void ana_kernel(const float* __restrict__ x,
                                                  const float* __restrict__ fana,
                                                  float* __restrict__ x3) {
  __shared__ float tileS[16 * 576];  // 16 ch x 24x24
  __shared__ float fs[729];
  int tid = threadIdx.x;
  int blk = blockIdx.x;
  int b = blk / 49;
  int tile = blk - b * 49;
  int y0 = (tile / 7) * 16, x0 = (tile % 7) * 16;

  for (int i = tid; i < 729; i += 256) fs[i] = fana[i];
  for (int idx = tid; idx < 9216; idx += 256) {
    int c = idx / 576, r = idx - c * 576;
    int ly = r / 24, lx = r - ly * 24;
    int gy = y0 + ly - 4, gx = x0 + lx - 4;
    float v = 0.f;
    if (gy >= 0 && gy < HH && gx >= 0 && gx < WW)
      v = fmaxf(x[(((long)b * CC + c) * HH + gy) * WW + gx], 0.f);
    tileS[idx] = v;
  }
  __syncthreads();

  int ty = tid >> 4, tx = tid & 15;
  long obase = (((long)b * HH + (y0 + ty)) * WW + (x0 + tx)) * DIM;
  for (int c = 0; c < 16; c++) {
    float acc[9];
#pragma unroll
    for (int k = 0; k < 9; k++) acc[k] = 0.f;
    const float* ts = &tileS[c * 576];
    for (int ky = 0; ky < 9; ky++)
      for (int kx = 0; kx < 9; kx++) {
        float v = ts[(ty + ky) * 24 + (tx + kx)];
#pragma unroll
        for (int k = 0; k < 9; k++) acc[k] += v * fs[k * 81 + ky * 9 + kx];
      }
    float skip = ts[(ty + 4) * 24 + (tx + 4)];
    float2* dst = (float2*)&x3[obase + c * 10];
    dst[0] = make_float2(acc[0], acc[1]);
    dst[1] = make_float2(acc[2], acc[3]);
    dst[2] = make_float2(acc[4], acc[5]);
    dst[3] = make_float2(acc[6], acc[7]);
    dst[4] = make_float2(acc[8], skip);
  }
}

// ---------------------------------------------------------------------------
// token_pos: window-ordered flat token p -> source position in [B,H,W]
// ---------------------------------------------------------------------------
__device__ __forceinline__ int token_pos(int p, int shift) {
  int w = p / 49;
  int t = p - w * 49;
  int b = w >> 8;
  int wid = w & 255;
  int wi = wid >> 4, wj = wid & 15;
  int iy = t / 7, ix = t - (t / 7) * 7;
  int hy = (wi * 7 + iy + shift) % HH;
  int wx = (wj * 7 + ix + shift) % WW;
  return (b * HH + hy) * WW + wx;
}

// ---------------------------------------------------------------------------
// Weight packing: fp32 [K x ncols] -> bf16 MFMA B-fragment-major layout.
// ---------------------------------------------------------------------------
__device__ __forceinline__ void pack_one(const float* __restrict__ src,
                                         unsigned short* __restrict__ dst,
                                         int nfcnt, int ncols, int nelems,
                                         int permK, int permN, int idx) {
  if (idx >= nelems) return;
  int j = idx & 7;
  int lane = (idx >> 3) & 63;
  int t = idx >> 9;
  int nf = t % nfcnt, ks = t / nfcnt;
  int k = ks * 32 + (lane >> 4) * 8 + j;
  int n = nf * 16 + (lane & 15);
  if (permK) k = orig_ch(k);
  if (permN) n = orig_ch(n);
  dst[idx] = f2bf(src[k * ncols + n]);
}

__global__ __launch_bounds__(256) void pack4_kernel(const float* __restrict__ qkvw,
                                                    const float* __restrict__ projw,
                                                    const float* __restrict__ w1,
                                                    const float* __restrict__ w2,
                                                    unsigned short* __restrict__ qkvf,
                                                    unsigned short* __restrict__ projf,
                                                    unsigned short* __restrict__ w1f,
                                                    unsigned short* __restrict__ w2f) {
  int blk = blockIdx.x, tid = threadIdx.x;
  if (blk < 300)      pack_one(qkvw,  qkvf,  30, 480, 76800,  1, 0, blk * 256 + tid);
  else if (blk < 400) pack_one(projw, projf, 10, 160, 25600,  0, 1, (blk - 300) * 256 + tid);
  else if (blk < 800) pack_one(w1,    w1f,   40, 640, 102400, 1, 0, (blk - 400) * 256 + tid);
  else                pack_one(w2,    w2f,   10, 160, 102400, 0, 1, (blk - 800) * 256 + tid);
}

__global__ __launch_bounds__(256) void pack1_kernel(const float* __restrict__ src,
                                                    unsigned short* __restrict__ dst,
                                                    int nfcnt, int ncols, int nelems,
                                                    int permK, int permN) {
  pack_one(src, dst, nfcnt, ncols, nelems, permK, permN, blockIdx.x * 256 + threadIdx.x);
}

// ---------------------------------------------------------------------------
// Kernel B1: LN1 + qkv GEMM via bf16 MFMA. 64 tokens/block (window-ordered).
// ---------------------------------------------------------------------------
__global__ __launch_bounds__(256) void qkv_mfma(const float* __restrict__ x3,
                                                const float* __restrict__ g,
                                                const float* __restrict__ bb,
                                                const unsigned short* __restrict__ qkvf,
                                                const float* __restrict__ qkvb,
                                                unsigned short* __restrict__ qkvbuf,
                                                int shift) {
  __shared__ unsigned short lnv[64 * 168];  // bf16, row stride 168

  int tid = threadIdx.x;
  int p0 = blockIdx.x * 64;

  // ---- LN1: 4 threads per token, 40 elems each (permuted channel space) ----
  {
    int t = tid >> 2, sub = tid & 3;
    int pos = token_pos(p0 + t, shift);
    const float* row = x3 + (long)pos * 160 + sub * 40;
    float xv[40];
    float s1 = 0.f, s2 = 0.f;
#pragma unroll
    for (int m = 0; m < 40; m++) { float v = row[m]; xv[m] = v; s1 += v; s2 += v * v; }
    s1 += __shfl_xor(s1, 1); s2 += __shfl_xor(s2, 1);
    s1 += __shfl_xor(s1, 2); s2 += __shfl_xor(s2, 2);
    float mu = s1 * (1.f / 160.f);
    float rs = rsqrtf(s2 * (1.f / 160.f) - mu * mu + 1e-5f);
#pragma unroll
    for (int m = 0; m < 40; m++) {
      int c = sub * 40 + m;
      int oc = orig_ch(c);
      lnv[t * 168 + c] = f2bf((xv[m] - mu) * rs * g[oc] + bb[oc]);
    }
  }
  __syncthreads();

  int w = tid >> 6, lane = tid & 63, quad = lane >> 4, l16 = lane & 15;

#pragma unroll
  for (int half = 0; half < 2; half++) {
    floatx4 acc[15];
#pragma unroll
    for (int n = 0; n < 15; n++) acc[n] = (floatx4){0.f, 0.f, 0.f, 0.f};
    for (int ks = 0; ks < 5; ks++) {
      short8 a = *(const short8*)&lnv[(w * 16 + l16) * 168 + ks * 32 + quad * 8];
      const short8* bp = (const short8*)qkvf + (ks * 30 + half * 15) * 64 + lane;
#pragma unroll
      for (int n = 0; n < 15; n++)
        acc[n] = __builtin_amdgcn_mfma_f32_16x16x32_bf16(a, bp[n * 64], acc[n], 0, 0, 0);
    }
#pragma unroll
    for (int n = 0; n < 15; n++) {
      int col = (half * 15 + n) * 16 + l16;
      float bv = qkvb[col];
#pragma unroll
      for (int r = 0; r < 4; r++) {
        int tok = p0 + w * 16 + quad * 4 + r;
        qkvbuf[(long)tok * 480 + col] = f2bf(acc[n][r] + bv);
      }
    }
  }
}

// ---------------------------------------------------------------------------
// Kernel B2: attention core, one block per (window, head), 128 threads.
// ---------------------------------------------------------------------------
__global__ __launch_bounds__(128) void attn_core(unsigned short* __restrict__ qkvbuf,
                                                 const float* __restrict__ rpb,
                                                 int shift) {
  __shared__ float qs[49 * 36], ksh[49 * 36], vsh[49 * 36];  // 16B-aligned rows
  __shared__ float pb[49 * 49];
  __shared__ float bias_s[169];

  int tid = threadIdx.x;
  int bid = blockIdx.x;
  int w = bid / 5, h = bid - (bid / 5) * 5;
  int wid = w & 255;
  int wi = wid >> 4, wj = wid & 15;
  long base = (long)w * 49 * 480;

  for (int i = tid; i < 169; i += 128) bias_s[i] = rpb[i * 5 + h];

  // load q,k,v [49,32] for this head, vectorized ushort4 -> float4
  for (int idx = tid; idx < 1176; idx += 128) {
    int m = idx / 392, r = idx - m * 392;
    int t = r >> 3, d4 = r & 7;
    ushort4 u = *(const ushort4*)&qkvbuf[base + (long)t * 480 + m * 160 + h * 32 + d4 * 4];
    float4 f = make_float4(bf2f(u.x), bf2f(u.y), bf2f(u.z), bf2f(u.w));
    float* dst = (m == 0) ? qs : (m == 1) ? ksh : vsh;
    *(float4*)&dst[t * 36 + d4 * 4] = f;
  }
  __syncthreads();

  // scores: thread (row i, half) with q-row cached in registers
  if (tid < 98) {
    int i = tid >> 1, halfj = tid & 1;
    int j0 = halfj * 25, jn = halfj ? 24 : 25;
    float4 qr[8];
#pragma unroll
    for (int d4 = 0; d4 < 8; d4++) qr[d4] = *(const float4*)&qs[i * 36 + d4 * 4];
    int iy = i / 7, ix = i - iy * 7;
    int hri = wi * 7 + iy, wri = wj * 7 + ix;
    int ai = hri < 105 ? 0 : (hri < 109 ? 1 : 2);
    int bi = wri < 105 ? 0 : (wri < 109 ? 1 : 2);
    for (int jj = 0; jj < jn; jj++) {
      int j = j0 + jj;
      float s = 0.f;
#pragma unroll
      for (int d4 = 0; d4 < 8; d4++) {
        float4 kr = *(const float4*)&ksh[j * 36 + d4 * 4];
        s += qr[d4].x * kr.x + qr[d4].y * kr.y + qr[d4].z * kr.z + qr[d4].w * kr.w;
      }
      s *= 0.17677669529663687f;
      int jy = j / 7, jx = j - jy * 7;
      int rel = (iy - jy + 6) * 13 + (ix - jx + 6);
      s += bias_s[rel];
      if (shift) {
        int hrj = wi * 7 + jy, wrj = wj * 7 + jx;
        int aj = hrj < 105 ? 0 : (hrj < 109 ? 1 : 2);
        int bj2 = wrj < 105 ? 0 : (wrj < 109 ? 1 : 2);
        if (ai != aj || bi != bj2) s -= 100.f;
      }
      pb[i * 49 + j] = s;
    }
  }
  __syncthreads();

  if (tid < 49) {
    float m = -1e30f;
    for (int j = 0; j < 49; j++) m = fmaxf(m, pb[tid * 49 + j]);
    float sum = 0.f;
    for (int j = 0; j < 49; j++) {
      float e = __expf(pb[tid * 49 + j] - m);
      pb[tid * 49 + j] = e;
      sum += e;
    }
    float inv = 1.f / sum;
    for (int j = 0; j < 49; j++) pb[tid * 49 + j] *= inv;
  }
  __syncthreads();

  // out = P @ V -> q-slot cols (bf16), vectorized
  for (int o = tid; o < 392; o += 128) {
    int i = o >> 3, d4 = o & 7;
    float4 a = make_float4(0.f, 0.f, 0.f, 0.f);
    for (int j = 0; j < 49; j++) {
      float p = pb[i * 49 + j];
      float4 v = *(const float4*)&vsh[j * 36 + d4 * 4];
      a.x += p * v.x; a.y += p * v.y; a.z += p * v.z; a.w += p * v.w;
    }
    ushort4 uo = make_ushort4(f2bf(a.x), f2bf(a.y), f2bf(a.z), f2bf(a.w));
    *(ushort4*)&qkvbuf[base + (long)i * 480 + h * 32 + d4 * 4] = uo;
  }
}

// ---------------------------------------------------------------------------
// Kernel B3: proj via bf16 MFMA + residual scatter-add. 64 tokens/block.
// ---------------------------------------------------------------------------
__global__ __launch_bounds__(256) void proj_mfma(const unsigned short* __restrict__ qkvbuf,
                                                 const unsigned short* __restrict__ projf,
                                                 const float* __restrict__ projb,
                                                 float* __restrict__ x3,
                                                 int shift) {
  __shared__ unsigned short ao[64 * 168];
  __shared__ int spos[64];
  int tid = threadIdx.x;
  int p0 = blockIdx.x * 64;
  if (tid < 64) spos[tid] = token_pos(p0 + tid, shift);
  for (int idx = tid; idx < 10240; idx += 256) {
    int t = idx / 160, ch = idx - t * 160;
    ao[t * 168 + ch] = qkvbuf[(long)(p0 + t) * 480 + ch];
  }
  __syncthreads();

  int w = tid >> 6, lane = tid & 63, quad = lane >> 4, l16 = lane & 15;
  floatx4 acc[10];
#pragma unroll
  for (int n = 0; n < 10; n++) acc[n] = (floatx4){0.f, 0.f, 0.f, 0.f};
  for (int ks = 0; ks < 5; ks++) {
    short8 a = *(const short8*)&ao[(w * 16 + l16) * 168 + ks * 32 + quad * 8];
    const short8* bp = (const short8*)projf + (ks * 10) * 64 + lane;
#pragma unroll
    for (int n = 0; n < 10; n++)
      acc[n] = __builtin_amdgcn_mfma_f32_16x16x32_bf16(a, bp[n * 64], acc[n], 0, 0, 0);
  }
#pragma unroll
  for (int n = 0; n < 10; n++) {
    int col = n * 16 + l16;           // permuted x3 channel
    float bv = projb[orig_ch(col)];
#pragma unroll
    for (int r = 0; r < 4; r++) {
      int tl = w * 16 + quad * 4 + r;
      long a = (long)spos[tl] * DIM + col;
      x3[a] = x3[a] + acc[n][r] + bv;
    }
  }
}

// ---------------------------------------------------------------------------
// Kernel C: LN2 + MLP via bf16 MFMA. 32 tokens/block, 4 waves.
// ---------------------------------------------------------------------------
__global__ __launch_bounds__(256) void mlp_mfma(float* __restrict__ x3,
                                                const float* __restrict__ g,
                                                const float* __restrict__ bb,
                                                const unsigned short* __restrict__ w1f,
                                                const float* __restrict__ b1,
                                                const unsigned short* __restrict__ w2f,
                                                const float* __restrict__ b2) {
  __shared__ unsigned short lnv[32 * 168];   // bf16, row stride 168
  __shared__ unsigned short h1s[32 * 648];   // bf16, row stride 648

  int tid = threadIdx.x;
  long p0 = (long)blockIdx.x * 32;

  // ---- LN2: 8 threads per token ----
  {
    int t = tid >> 3, sub = tid & 7;
    const float* row = x3 + (p0 + t) * 160 + sub * 20;
    float xv[20];
    float s1 = 0.f, s2 = 0.f;
#pragma unroll
    for (int m = 0; m < 20; m++) { float v = row[m]; xv[m] = v; s1 += v; s2 += v * v; }
#pragma unroll
    for (int m = 1; m < 8; m <<= 1) { s1 += __shfl_xor(s1, m); s2 += __shfl_xor(s2, m); }
    float mu = s1 * (1.f / 160.f);
    float rs = rsqrtf(s2 * (1.f / 160.f) - mu * mu + 1e-5f);
#pragma unroll
    for (int m = 0; m < 20; m++) {
      int c = sub * 20 + m;
      int oc = orig_ch(c);
      lnv[t * 168 + c] = f2bf((xv[m] - mu) * rs * g[oc] + bb[oc]);
    }
  }
  __syncthreads();

  int w = tid >> 6, lane = tid & 63, quad = lane >> 4, l16 = lane & 15;

  // ---- fc1: wave w -> cols [w*160, w*160+160) ----
  floatx4 acc[2][10];
#pragma unroll
  for (int mf = 0; mf < 2; mf++)
#pragma unroll
    for (int n = 0; n < 10; n++) acc[mf][n] = (floatx4){0.f, 0.f, 0.f, 0.f};

  for (int ks = 0; ks < 5; ks++) {
    short8 a0 = *(const short8*)&lnv[l16 * 168 + ks * 32 + quad * 8];
    short8 a1 = *(const short8*)&lnv[(16 + l16) * 168 + ks * 32 + quad * 8];
    const short8* bp = (const short8*)w1f + (ks * 40 + w * 10) * 64 + lane;
#pragma unroll
    for (int n = 0; n < 10; n++) {
      short8 bf = bp[n * 64];
      acc[0][n] = __builtin_amdgcn_mfma_f32_16x16x32_bf16(a0, bf, acc[0][n], 0, 0, 0);
      acc[1][n] = __builtin_amdgcn_mfma_f32_16x16x32_bf16(a1, bf, acc[1][n], 0, 0, 0);
    }
  }

  // fc1 epilogue: bias + gelu -> h1s (bf16)
#pragma unroll
  for (int mf = 0; mf < 2; mf++)
#pragma unroll
    for (int n = 0; n < 10; n++) {
      int col = w * 160 + n * 16 + l16;
      float bv = b1[col];
#pragma unroll
      for (int r = 0; r < 4; r++) {
        int tok = mf * 16 + quad * 4 + r;
        h1s[tok * 648 + col] = f2bf(gelu_f(acc[mf][n][r] + bv));
      }
    }
  __syncthreads();

  // ---- fc2: wave w -> M-frag (w&1), N-frags [(w>>1)*5 .. +5), full K ----
  int mf = w & 1, nb = (w >> 1) * 5;
  floatx4 acc2[5];
#pragma unroll
  for (int n = 0; n < 5; n++) acc2[n] = (floatx4){0.f, 0.f, 0.f, 0.f};
  for (int ks = 0; ks < 20; ks++) {
    short8 a = *(const short8*)&h1s[(mf * 16 + l16) * 648 + ks * 32 + quad * 8];
    const short8* bp = (const short8*)w2f + (ks * 10 + nb) * 64 + lane;
#pragma unroll
    for (int n = 0; n < 5; n++)
      acc2[n] = __builtin_amdgcn_mfma_f32_16x16x32_bf16(a, bp[n * 64], acc2[n], 0, 0, 0);
  }

  // residual + bias writeout
#pragma unroll
  for (int n = 0; n < 5; n++) {
    int col = (nb + n) * 16 + l16;    // permuted x3 channel
    float bv = b2[orig_ch(col)];
#pragma unroll
    for (int r = 0; r < 4; r++) {
      int tok = mf * 16 + quad * 4 + r;
      long a = (p0 + tok) * 160 + col;
      x3[a] = x3[a] + acc2[n][r] + bv;
    }
  }
}

// ---------------------------------------------------------------------------
// Kernel D: lin via bf16 MFMA -> plane-major yp [144][NPOS].
// 64 tokens/block, 4 waves x one M-frag; K=160 (permuted), N=144 (9 frags).
// ---------------------------------------------------------------------------
__global__ __launch_bounds__(256) void lin_mfma(const float* __restrict__ x3,
                                                const unsigned short* __restrict__ linf,
                                                const float* __restrict__ linb,
                                                float* __restrict__ yp) {
  __shared__ unsigned short xs[64 * 168];  // bf16, row stride 168
  int tid = threadIdx.x;
  int p0 = blockIdx.x * 64;

  // stage 64 tokens x 160 ch, fp32 -> bf16 (float2 loads, ushort2 stores)
  for (int idx = tid; idx < 5120; idx += 256) {
    int t = idx / 80, c2 = idx - t * 80;
    float2 v = *(const float2*)&x3[((long)(p0 + t)) * 160 + c2 * 2];
    *(ushort2*)&xs[t * 168 + c2 * 2] = make_ushort2(f2bf(v.x), f2bf(v.y));
  }
  __syncthreads();

  int w = tid >> 6, lane = tid & 63, quad = lane >> 4, l16 = lane & 15;
  floatx4 acc[9];
#pragma unroll
  for (int n = 0; n < 9; n++) acc[n] = (floatx4){0.f, 0.f, 0.f, 0.f};
  for (int ks = 0; ks < 5; ks++) {
    short8 a = *(const short8*)&xs[(w * 16 + l16) * 168 + ks * 32 + quad * 8];
    const short8* bp = (const short8*)linf + (ks * 9) * 64 + lane;
#pragma unroll
    for (int n = 0; n < 9; n++)
      acc[n] = __builtin_amdgcn_mfma_f32_16x16x32_bf16(a, bp[n * 64], acc[n], 0, 0, 0);
  }
#pragma unroll
  for (int n = 0; n < 9; n++) {
    int col = n * 16 + l16;
    float bv = linb[col];
    float4 o = make_float4(acc[n][0] + bv, acc[n][1] + bv, acc[n][2] + bv, acc[n][3] + bv);
    *(float4*)&yp[(long)col * NPOS + p0 + w * 16 + quad * 4] = o;
  }
}

// ---------------------------------------------------------------------------
// Kernel E: synthesis conv, sliding-window register blocking.
// ---------------------------------------------------------------------------
__global__ __launch_bounds__(256) void syn_kernel(const float* __restrict__ yp,
                                                  const float* __restrict__ fsyn,
                                                  float* __restrict__ yt) {
  __shared__ float tileS[24 * 120];  // one plane halo: 24 rows x 120 cols
  __shared__ float fsl[729];
  int tid = threadIdx.x;
  int blk = blockIdx.x;
  int tile = blk % 7;                 // row tile (16 rows)
  int c = (blk / 7) % 16;
  int b = blk / 112;
  int ty0 = tile * 16;

  for (int i = tid; i < 729; i += 256) fsl[i] = fsyn[i];

  int ty = tid >> 4, txg = tid & 15;  // output row 0..15, col-group 0..15
  float acc[7];
#pragma unroll
  for (int w = 0; w < 7; w++) acc[w] = 0.f;

  for (int k = 0; k < 9; k++) {
    const float* plane = yp + (long)(k * 16 + c) * NPOS + (long)b * HH * WW;
    __syncthreads();  // previous compute done before overwrite
    for (int idx = tid; idx < 2880; idx += 256) {
      int ly = idx / 120, lx = idx - ly * 120;
      int gy = ty0 + ly - 4, gx = lx - 4;
      float v = 0.f;
      if (gy >= 0 && gy < HH && gx >= 0 && gx < WW) v = plane[gy * WW + gx];
      tileS[idx] = v;
    }
    __syncthreads();

#pragma unroll
    for (int ky = 0; ky < 9; ky++) {
      const float* row = &tileS[(ty + ky) * 120 + txg * 7];
      float rr[15];
#pragma unroll
      for (int i = 0; i < 15; i++) rr[i] = row[i];
      const float* fk = &fsl[k * 81 + ky * 9];
#pragma unroll
      for (int kx = 0; kx < 9; kx++) {
        float f = fk[kx];
#pragma unroll
        for (int w = 0; w < 7; w++) acc[w] += rr[kx + w] * f;
      }
    }
  }

  long obase = (long)c * NPOS + ((long)b * HH + (ty0 + ty)) * WW + txg * 7;
#pragma unroll
  for (int w = 0; w < 7; w++) yt[obase + w] = acc[w];
}

// ---------------------------------------------------------------------------
// Kernel F: final 1x1 conv from plane-major inputs -> out [B,16,H,W]
// ---------------------------------------------------------------------------
__global__ __launch_bounds__(256) void final_kernel(const float* __restrict__ yt,
                                                    const float* __restrict__ yp,
                                                    const float* __restrict__ convw,
                                                    const float* __restrict__ convb,
                                                    float* __restrict__ out) {
  long pos = (long)blockIdx.x * 256 + threadIdx.x;
  if (pos >= NPOS) return;
  int b = (int)(pos / (HH * WW));
  int hw = (int)(pos - (long)b * HH * WW);

  float acc[16];
#pragma unroll
  for (int co = 0; co < 16; co++) acc[co] = convb[co];
  for (int c = 0; c < 16; c++) {
    float v = yt[(long)c * NPOS + pos];
#pragma unroll
    for (int co = 0; co < 16; co++) acc[co] += v * convw[co * 160 + c];
  }
  for (int j = 0; j < 144; j++) {
    float v = yp[(long)j * NPOS + pos];
#pragma unroll
    for (int co = 0; co < 16; co++) acc[co] += v * convw[co * 160 + 16 + j];
  }
#pragma unroll
  for (int co = 0; co < 16; co++)
    out[(((long)b * 16 + co) * HH * WW) + hw] = acc[co];
}

// ---------------------------------------------------------------------------
extern "C" void kernel_launch(void* const* d_in, const int* in_sizes, int n_in,
                              void* d_out, int out_size, void* d_ws, size_t ws_size,
                              hipStream_t stream) {
  const float* x     = (const float*)d_in[0];
  const float* fana  = (const float*)d_in[1];
  const float* fsyn  = (const float*)d_in[2];
  const float* ln1g  = (const float*)d_in[3];
  const float* ln1b  = (const float*)d_in[4];
  const float* qkvw  = (const float*)d_in[5];
  const float* qkvb  = (const float*)d_in[6];
  const float* projw = (const float*)d_in[7];
  const float* projb = (const float*)d_in[8];
  const float* rpb   = (const float*)d_in[9];
  const float* ln2g  = (const float*)d_in[10];
  const float* ln2b  = (const float*)d_in[11];
  const float* w1    = (const float*)d_in[12];
  const float* b1    = (const float*)d_in[13];
  const float* w2    = (const float*)d_in[14];
  const float* b2    = (const float*)d_in[15];
  const float* linw  = (const float*)d_in[16];
  const float* linb  = (const float*)d_in[17];
  const float* convw = (const float*)d_in[18];
  const float* convb = (const float*)d_in[19];
  float* out = (float*)d_out;

  char* ws = (char*)d_ws;
  float* x3 = (float*)ws;                           // 64,225,280 B, live whole run
  char* region2 = ws + 64225280;                    // time-shared:
  unsigned short* qkvbuf = (unsigned short*)region2;           // bf16 [NPOS x 480]
  unsigned short* packs  = (unsigned short*)(region2 + 96337920);
  unsigned short* qkvf = packs;                     // 76800 ush
  unsigned short* projf = packs + 76800;            // 25600 ush
  unsigned short* w1f   = packs + 102400;           // 102400 ush
  unsigned short* w2f   = packs + 204800;           // 102400 ush
  unsigned short* linf  = packs + 307200;           // 23040 ush (outlives swin loop)
  float* yp = (float*)region2;                      // lin/syn/final phase (57.8 MB < qkvbuf)
  float* yt = (float*)ws;                           // aliases x3 (dead after lin)

  ana_kernel<<<BB * 49, 256, 0, stream>>>(x, fana, x3);
  pack1_kernel<<<90, 256, 0, stream>>>(linw, linf, 9, 144, 23040, 1, 0);
  for (int i = 0; i < 2; i++) {
    int shift = i ? (WIN / 2) : 0;
    pack4_kernel<<<1200, 256, 0, stream>>>(qkvw + i * 76800, projw + i * 25600,
                                           w1 + i * 102400, w2 + i * 102400,
                                           qkvf, projf, w1f, w2f);
    qkv_mfma<<<NPOS / 64, 256, 0, stream>>>(x3, ln1g + i * 160, ln1b + i * 160,
                                            qkvf, qkvb + i * 480, qkvbuf, shift);
    attn_core<<<BB * NWIN * HEADS, 128, 0, stream>>>(qkvbuf, rpb + i * 169 * 5, shift);
    proj_mfma<<<NPOS / 64, 256, 0, stream>>>(qkvbuf, projf, projb + i * 160, x3, shift);
    mlp_mfma<<<NPOS / 32, 256, 0, stream>>>(x3, ln2g + i * 160, ln2b + i * 160,
                                            w1f, b1 + i * 640, w2f, b2 + i * 160);
  }
  lin_mfma<<<NPOS / 64, 256, 0, stream>>>(x3, linf, linb, yp);
  syn_kernel<<<BB * 16 * 7, 256, 0, stream>>>(yp, fsyn, yt);
  final_kernel<<<(NPOS + 255) / 256, 256, 0, stream>>>(yt, yp, convw, convb, out);
}